// Round 7
// baseline (346.765 us; speedup 1.0000x reference)
//
#include <hip/hip_runtime.h>
#include <hip/hip_bf16.h>

#define S_TOT 32768
#define C_IN 192
#define NB 2
#define NH 8
#define DH 64
#define ATT_SCALE 0.125f
#define NSLICE 128
#define GR_CH 8
#define GR_BK 32

// ---------------- workspace layout (float units) ----------------
#define G_OFF   0
#define G_SZ    (NB * C_IN * C_IN)
#define T_OFF   (G_OFF + G_SZ)
#define T_SZ    (NB * 512 * C_IN)
#define M_OFF   (T_OFF + T_SZ)
#define M_SZ    (NB * 512 * C_IN)
#define WBF_OFF (M_OFF + M_SZ)
#define WBF_SZ  (NB * C_IN * C_IN / 2)
#define P_OFF   (WBF_OFF + WBF_SZ)
#define P_SZ    (NB * NSLICE * C_IN * C_IN)

// split-weight / split-G / split-Z storage (each array = N ushorts = N/2 floats)
#define WEL      (512 * C_IN)
#define SPL_FL   (WEL / 2)
#define WQH_OFF  (P_OFF + P_SZ)
#define WQM_OFF  (WQH_OFF + SPL_FL)
#define WQL_OFF  (WQM_OFF + SPL_FL)
#define WKH_OFF  (WQL_OFF + SPL_FL)
#define WKM_OFF  (WKH_OFF + SPL_FL)
#define WKL_OFF  (WKM_OFF + SPL_FL)
#define WOH_OFF  (WKL_OFF + SPL_FL)
#define WOL_OFF  (WOH_OFF + SPL_FL)
#define WVTH_OFF (WOL_OFF + SPL_FL)
#define WVTL_OFF (WVTH_OFF + SPL_FL)
#define GEL      (C_IN * C_IN)
#define GH_OFF   (WVTL_OFF + SPL_FL)
#define GM_OFF   (GH_OFF + NB * GEL / 2)
#define GL_OFF   (GM_OFF + NB * GEL / 2)
#define ZEL      (C_IN * 512)
#define ZH_OFF   (GL_OFF + NB * GEL / 2)
#define ZL_OFF   (ZH_OFF + NB * ZEL / 2)

// barrier state: 5 instances x (144 arrival lines + 1 release line) x 16 uints
#define BAR_STRIDE 2336
#define BAR_OFF  (ZL_OFF + NB * ZEL / 2)
#define BAR_SZ   (5 * BAR_STRIDE)
#define WS_END   (BAR_OFF + BAR_SZ)

// Regions aliased into the (dead after phase A) P region:
#define PT_EL    (512 * C_IN)
#define QTH_OFF  (P_OFF)
#define QTM_OFF  (QTH_OFF + NB * PT_EL / 2)
#define QTL_OFF  (QTM_OFF + NB * PT_EL / 2)
#define WMX_OFF  (QTL_OFF + NB * PT_EL / 2)   // 8 * NB * GEL fp32 partials (phase D)

// Phase-A fp32 partials: aliased into the T region (unused on the bigws path).
// 2 slice-groups x NB x GEL = 147456 floats <= T_SZ = 196608.  MUST NOT alias P!
#define PA_OFF   T_OFF
#define PA_SG    2

#define MEGA_NBLK 144   // 144 x 256thr; PA work = 144*256 = 36864 items exactly

typedef __attribute__((ext_vector_type(8))) short short8;
typedef __attribute__((ext_vector_type(4))) float f32x4;

__device__ inline unsigned short f2bf(float f) {   // RNE
    unsigned int u = __float_as_uint(f);
    u += 0x7fffu + ((u >> 16) & 1u);
    return (unsigned short)(u >> 16);
}

__device__ inline unsigned int pk_bf16(float a, float b) {  // packed RNE pair
    __hip_bfloat162 t = __float22bfloat162_rn(make_float2(a, b));
    unsigned int bits;
    __builtin_memcpy(&bits, &t, 4);
    return bits;
}

__device__ inline void split_bf(float v, unsigned short& h, unsigned short& l) {
    unsigned int u = __float_as_uint(v);
    h = (unsigned short)(u >> 16);
    float hf = __uint_as_float(u & 0xffff0000u);
    l = f2bf(v - hf);
}

__device__ inline void split3_bf(float v, unsigned short& h, unsigned short& m, unsigned short& l) {
    unsigned int u = __float_as_uint(v);
    h = (unsigned short)(u >> 16);
    float hf = __uint_as_float(u & 0xffff0000u);
    float r1 = v - hf;
    unsigned int u1 = __float_as_uint(r1);
    m = (unsigned short)(u1 >> 16);
    float mf = __uint_as_float(u1 & 0xffff0000u);
    l = f2bf(r1 - mf);
}

__device__ inline unsigned long long pack4(const unsigned short* s) {
    return (unsigned long long)s[0] | ((unsigned long long)s[1] << 16)
         | ((unsigned long long)s[2] << 32) | ((unsigned long long)s[3] << 48);
}

// Software grid barrier, store/poll form — NO same-line RMWs.
// Rounds 4-6 showed arrival atomicAdds to one line serialize at ~220ns each
// (32 us per barrier at 144 blocks). Here: each block's leader STORES to its
// own cache line (parallel); block 0's threads poll the 144 distinct lines
// (parallel loads); block 0 then publishes a release flag (read-only polls).
// State zeroed by the PREVIOUS dispatch -> graph replay re-initializes.
__device__ inline void gbar(unsigned int* bar) {
    __syncthreads();
    if (blockIdx.x == 0) {
        if (threadIdx.x > 0 && threadIdx.x < MEGA_NBLK) {
            while (__hip_atomic_load(bar + threadIdx.x * 16, __ATOMIC_ACQUIRE,
                                     __HIP_MEMORY_SCOPE_AGENT) == 0u)
                __builtin_amdgcn_s_sleep(1);
        }
        __syncthreads();
        if (threadIdx.x == 0) {
            __threadfence();  // block 0's own phase writes device-visible
            __hip_atomic_store(bar + MEGA_NBLK * 16, 1u, __ATOMIC_RELEASE,
                               __HIP_MEMORY_SCOPE_AGENT);
        }
    } else {
        if (threadIdx.x == 0) {
            __threadfence();  // this block's phase writes device-visible
            __hip_atomic_store(bar + blockIdx.x * 16, 1u, __ATOMIC_RELEASE,
                               __HIP_MEMORY_SCOPE_AGENT);
            while (__hip_atomic_load(bar + MEGA_NBLK * 16, __ATOMIC_ACQUIRE,
                                     __HIP_MEMORY_SCOPE_AGENT) == 0u)
                __builtin_amdgcn_s_sleep(2);
        }
    }
    __syncthreads();
    __threadfence();  // acquire side: discard stale cached lines before reading
}

// One unit of weight pre-splitting; 98304 units over gram_partial's 256 blocks x 384 lanes.
__device__ inline void split_unit(int u, const float* wq, const float* wk,
                                  const float* wv, const float* wo, float* ws) {
    int region = u / 24576;
    int r = u - region * 24576;
    if (region < 3) {
        const float* src = (region == 0) ? wq : (region == 1) ? wk : wo;
        int i = r * 4;
        float4 v = *(const float4*)(src + i);
        if (region < 2) {
            unsigned short h[4], m[4], l[4];
            split3_bf(v.x, h[0], m[0], l[0]);
            split3_bf(v.y, h[1], m[1], l[1]);
            split3_bf(v.z, h[2], m[2], l[2]);
            split3_bf(v.w, h[3], m[3], l[3]);
            int base = (region == 0) ? WQH_OFF : WKH_OFF;
            *(unsigned long long*)((unsigned short*)(ws + base) + i)              = pack4(h);
            *(unsigned long long*)((unsigned short*)(ws + base + SPL_FL) + i)     = pack4(m);
            *(unsigned long long*)((unsigned short*)(ws + base + 2 * SPL_FL) + i) = pack4(l);
        } else {
            unsigned short h[4], l[4];
            split_bf(v.x, h[0], l[0]);
            split_bf(v.y, h[1], l[1]);
            split_bf(v.z, h[2], l[2]);
            split_bf(v.w, h[3], l[3]);
            *(unsigned long long*)((unsigned short*)(ws + WOH_OFF) + i) = pack4(h);
            *(unsigned long long*)((unsigned short*)(ws + WOL_OFF) + i) = pack4(l);
        }
    } else {
        int j4 = r / 192;
        int c  = r - j4 * 192;
        int j  = j4 * 4;
        unsigned short h[4], l[4];
#pragma unroll
        for (int jj = 0; jj < 4; ++jj)
            split_bf(wv[(size_t)(j + jj) * C_IN + c], h[jj], l[jj]);
        *(unsigned long long*)((unsigned short*)(ws + WVTH_OFF) + c * 512 + j) = pack4(h);
        *(unsigned long long*)((unsigned short*)(ws + WVTL_OFF) + c * 512 + j) = pack4(l);
    }
}

// ---------------- Gram via split-bf16 MFMA: P[b][slice] = X-slice * X-slice^T ----------------
__global__ __launch_bounds__(512, 2) void gram_partial(const float* __restrict__ x,
                                                       const float* __restrict__ wq,
                                                       const float* __restrict__ wk,
                                                       const float* __restrict__ wv,
                                                       const float* __restrict__ wo,
                                                       float* __restrict__ ws) {
    int b     = blockIdx.y;
    int slice = blockIdx.x;
    int kbase = slice * (GR_CH * GR_BK);

    __shared__ unsigned short Hs[192 * 40];
    __shared__ unsigned short Lo[192 * 40];

    int tid  = threadIdx.x;
    int wave = tid >> 6;
    int lane = tid & 63;
    int rw   = wave & 3;
    int cw   = wave >> 2;
    int lm   = lane & 15, quad = lane >> 4;

    // zero the mega_mid barrier state for this iteration (visible at next dispatch)
    if (blockIdx.x == 0 && blockIdx.y == 0) {
        unsigned int* bz = (unsigned int*)(ws + BAR_OFF);
        for (int u = tid; u < BAR_SZ; u += 512) bz[u] = 0u;
    }

    const float* xb = x + (size_t)b * C_IN * S_TOT;

    int lc[3], lkq[3];
#pragma unroll
    for (int q = 0; q < 3; q++) { int id = tid + 512 * q; lc[q] = id >> 3; lkq[q] = id & 7; }

    f32x4 acc[3][6];
#pragma unroll
    for (int mt = 0; mt < 3; mt++)
#pragma unroll
        for (int nt = 0; nt < 6; nt++) acc[mt][nt] = (f32x4){0.f, 0.f, 0.f, 0.f};

    float4 pf[3];
#pragma unroll
    for (int q = 0; q < 3; q++)
        pf[q] = *(const float4*)(xb + (size_t)lc[q] * S_TOT + kbase + lkq[q] * 4);

    if (tid < 384) split_unit((b * NSLICE + slice) * 384 + tid, wq, wk, wv, wo, ws);

    for (int ch = 0; ch < GR_CH; ++ch) {
        __syncthreads();
#pragma unroll
        for (int q = 0; q < 3; q++) {
            unsigned short h[4], l[4];
            split_bf(pf[q].x, h[0], l[0]);
            split_bf(pf[q].y, h[1], l[1]);
            split_bf(pf[q].z, h[2], l[2]);
            split_bf(pf[q].w, h[3], l[3]);
            *(unsigned long long*)&Hs[lc[q] * 40 + lkq[q] * 4] = pack4(h);
            *(unsigned long long*)&Lo[lc[q] * 40 + lkq[q] * 4] = pack4(l);
        }
        __syncthreads();
        if (ch + 1 < GR_CH) {
            int k0 = kbase + (ch + 1) * GR_BK;
#pragma unroll
            for (int q = 0; q < 3; q++)
                pf[q] = *(const float4*)(xb + (size_t)lc[q] * S_TOT + k0 + lkq[q] * 4);
        }

        short8 ah[3], al[3];
#pragma unroll
        for (int mt = 0; mt < 3; mt++) {
            int row = 48 * rw + mt * 16 + lm;
            ah[mt] = *(const short8*)&Hs[row * 40 + quad * 8];
            al[mt] = *(const short8*)&Lo[row * 40 + quad * 8];
        }
#pragma unroll
        for (int nt = 0; nt < 6; nt++) {
            int col = 96 * cw + nt * 16 + lm;
            short8 bh = *(const short8*)&Hs[col * 40 + quad * 8];
            short8 bl = *(const short8*)&Lo[col * 40 + quad * 8];
#pragma unroll
            for (int mt = 0; mt < 3; mt++) {
                acc[mt][nt] = __builtin_amdgcn_mfma_f32_16x16x32_bf16(ah[mt], bh, acc[mt][nt], 0, 0, 0);
                acc[mt][nt] = __builtin_amdgcn_mfma_f32_16x16x32_bf16(ah[mt], bl, acc[mt][nt], 0, 0, 0);
                acc[mt][nt] = __builtin_amdgcn_mfma_f32_16x16x32_bf16(al[mt], bh, acc[mt][nt], 0, 0, 0);
            }
        }
    }

    float* Pb = ws + P_OFF + ((size_t)(b * NSLICE + slice)) * (C_IN * C_IN);
#pragma unroll
    for (int mt = 0; mt < 3; mt++) {
#pragma unroll
        for (int r = 0; r < 4; r++) {
            int row = 48 * rw + mt * 16 + quad * 4 + r;
#pragma unroll
            for (int nt = 0; nt < 6; nt++)
                Pb[row * C_IN + 96 * cw + nt * 16 + lm] = acc[mt][nt][r];
        }
    }
}

// ---------------- middle: reduce -> proj -> attn -> wmix -> pack (one dispatch) ----------------
// grid 144 x block 256; phases separated by store/poll grid barrier (gbar).
__global__ __launch_bounds__(256) void mega_mid(float* __restrict__ ws) {
    unsigned int* bars = (unsigned int*)(ws + BAR_OFF);
    int bid  = blockIdx.x;
    int tid  = threadIdx.x;
    int wave = tid >> 6;
    int lane = tid & 63;
    int lm   = lane & 15, quad = lane >> 4;

    __shared__ float At[64 * 68];

    // ======== Phase A: reduce P (64 slices/thread, 8x8-deep) -> fp32 partials (T region) ========
    // 36864 items = 144 blocks x 256 thr exactly.
    {
        int gid = bid * 256 + tid;
        int sg  = gid / (NB * (GEL / 4));
        int rem = gid - sg * (NB * (GEL / 4));
        int b   = rem / (GEL / 4);
        int idx4 = (rem - b * (GEL / 4)) * 4;
        const float* Pb = ws + P_OFF + ((size_t)(b * NSLICE + sg * 64)) * GEL + idx4;
        float4 acc = {0.f, 0.f, 0.f, 0.f};
#pragma unroll
        for (int t = 0; t < 8; ++t) {
            const float* p = Pb + (size_t)(t * 8) * GEL;
            float4 v0 = *(const float4*)(p + 0 * (size_t)GEL);
            float4 v1 = *(const float4*)(p + 1 * (size_t)GEL);
            float4 v2 = *(const float4*)(p + 2 * (size_t)GEL);
            float4 v3 = *(const float4*)(p + 3 * (size_t)GEL);
            float4 v4 = *(const float4*)(p + 4 * (size_t)GEL);
            float4 v5 = *(const float4*)(p + 5 * (size_t)GEL);
            float4 v6 = *(const float4*)(p + 6 * (size_t)GEL);
            float4 v7 = *(const float4*)(p + 7 * (size_t)GEL);
            acc.x += v0.x; acc.y += v0.y; acc.z += v0.z; acc.w += v0.w;
            acc.x += v1.x; acc.y += v1.y; acc.z += v1.z; acc.w += v1.w;
            acc.x += v2.x; acc.y += v2.y; acc.z += v2.z; acc.w += v2.w;
            acc.x += v3.x; acc.y += v3.y; acc.z += v3.z; acc.w += v3.w;
            acc.x += v4.x; acc.y += v4.y; acc.z += v4.z; acc.w += v4.w;
            acc.x += v5.x; acc.y += v5.y; acc.z += v5.z; acc.w += v5.w;
            acc.x += v6.x; acc.y += v6.y; acc.z += v6.z; acc.w += v6.w;
            acc.x += v7.x; acc.y += v7.y; acc.z += v7.z; acc.w += v7.w;
        }
        *(float4*)(ws + PA_OFF + (size_t)(sg * NB + b) * GEL + idx4) = acc;
    }
    gbar(bars + 0 * BAR_STRIDE);

    // ======== Phase A2: sum 2 slice-group partials -> triple-split G ========
    {
        int gid = bid * 256 + tid;
        if (gid < NB * (GEL / 4)) {
            int b = gid / (GEL / 4);
            int idx4 = (gid - b * (GEL / 4)) * 4;
            const float* Pp = ws + PA_OFF + (size_t)b * GEL + idx4;
            float4 p0 = *(const float4*)(Pp);
            float4 p1 = *(const float4*)(Pp + (size_t)(NB * GEL));
            float4 s;
            s.x = p0.x + p1.x;
            s.y = p0.y + p1.y;
            s.z = p0.z + p1.z;
            s.w = p0.w + p1.w;
            unsigned short h[4], m[4], l[4];
            split3_bf(s.x, h[0], m[0], l[0]);
            split3_bf(s.y, h[1], m[1], l[1]);
            split3_bf(s.z, h[2], m[2], l[2]);
            split3_bf(s.w, h[3], m[3], l[3]);
            *(unsigned long long*)((unsigned short*)(ws + GH_OFF) + (size_t)b * GEL + idx4) = pack4(h);
            *(unsigned long long*)((unsigned short*)(ws + GM_OFF) + (size_t)b * GEL + idx4) = pack4(m);
            *(unsigned long long*)((unsigned short*)(ws + GL_OFF) + (size_t)b * GEL + idx4) = pack4(l);
        }
    }
    gbar(bars + 1 * BAR_STRIDE);

    // ======== Phase B: Qt = Wq * G (6-term triple MFMA), triple-split out ========
    if (bid < 32) {
        int b = bid & 1, h = (bid >> 1) & 7, cgi = (bid >> 4) & 1;
        const unsigned short* AH = (const unsigned short*)(ws + WQH_OFF);
        const unsigned short* AM = (const unsigned short*)(ws + WQM_OFF);
        const unsigned short* AL = (const unsigned short*)(ws + WQL_OFF);
        const unsigned short* GH = (const unsigned short*)(ws + GH_OFF) + (size_t)b * GEL;
        const unsigned short* GM = (const unsigned short*)(ws + GM_OFF) + (size_t)b * GEL;
        const unsigned short* GL = (const unsigned short*)(ws + GL_OFF) + (size_t)b * GEL;

        int arow = (h * 64 + wave * 16 + lm) * C_IN;

        f32x4 qacc[6];
#pragma unroll
        for (int ct = 0; ct < 6; ++ct) qacc[ct] = (f32x4){0.f, 0.f, 0.f, 0.f};

#pragma unroll
        for (int ch = 0; ch < 6; ++ch) {
            int k0 = ch * 32 + quad * 8;
            short8 aH = *(const short8*)(AH + arow + k0);
            short8 aM = *(const short8*)(AM + arow + k0);
            short8 aL = *(const short8*)(AL + arow + k0);
            short8 bH[6], bM[6], bL[6];
#pragma unroll
            for (int ct = 0; ct < 6; ++ct) {
                int gr = (cgi * 96 + ct * 16 + lm) * C_IN + k0;
                bH[ct] = *(const short8*)(GH + gr);
                bM[ct] = *(const short8*)(GM + gr);
                bL[ct] = *(const short8*)(GL + gr);
            }
#pragma unroll
            for (int ct = 0; ct < 6; ++ct) {
                qacc[ct] = __builtin_amdgcn_mfma_f32_16x16x32_bf16(aH, bH[ct], qacc[ct], 0, 0, 0);
                qacc[ct] = __builtin_amdgcn_mfma_f32_16x16x32_bf16(aH, bM[ct], qacc[ct], 0, 0, 0);
                qacc[ct] = __builtin_amdgcn_mfma_f32_16x16x32_bf16(aM, bH[ct], qacc[ct], 0, 0, 0);
                qacc[ct] = __builtin_amdgcn_mfma_f32_16x16x32_bf16(aH, bL[ct], qacc[ct], 0, 0, 0);
                qacc[ct] = __builtin_amdgcn_mfma_f32_16x16x32_bf16(aM, bM[ct], qacc[ct], 0, 0, 0);
                qacc[ct] = __builtin_amdgcn_mfma_f32_16x16x32_bf16(aL, bH[ct], qacc[ct], 0, 0, 0);
            }
        }

        unsigned short* QH = (unsigned short*)(ws + QTH_OFF) + (size_t)b * PT_EL;
        unsigned short* QM = (unsigned short*)(ws + QTM_OFF) + (size_t)b * PT_EL;
        unsigned short* QL = (unsigned short*)(ws + QTL_OFF) + (size_t)b * PT_EL;
#pragma unroll
        for (int ct = 0; ct < 6; ++ct)
#pragma unroll
            for (int r = 0; r < 4; ++r) {
                int row = h * 64 + wave * 16 + quad * 4 + r;
                int col = cgi * 96 + ct * 16 + lm;
                unsigned short hh, mm, ll;
                split3_bf(qacc[ct][r], hh, mm, ll);
                QH[row * C_IN + col] = hh;
                QM[row * C_IN + col] = mm;
                QL[row * C_IN + col] = ll;
            }
    }
    gbar(bars + 2 * BAR_STRIDE);

    // ======== Phase C: sim = Qt_h*Wk_h^T -> softmax -> Z_h = Wo_h*attn ========
    if (bid < 16) {
        int b = bid & 1, h = bid >> 1;

        const unsigned short* QH = (const unsigned short*)(ws + QTH_OFF) + (size_t)b * PT_EL;
        const unsigned short* QM = (const unsigned short*)(ws + QTM_OFF) + (size_t)b * PT_EL;
        const unsigned short* QL = (const unsigned short*)(ws + QTL_OFF) + (size_t)b * PT_EL;
        const unsigned short* KH = (const unsigned short*)(ws + WKH_OFF);
        const unsigned short* KM = (const unsigned short*)(ws + WKM_OFF);
        const unsigned short* KL = (const unsigned short*)(ws + WKL_OFF);
        const unsigned short* WOHp = (const unsigned short*)(ws + WOH_OFF);
        const unsigned short* WOLp = (const unsigned short*)(ws + WOL_OFF);

        f32x4 sacc[4];
#pragma unroll
        for (int ct = 0; ct < 4; ++ct) sacc[ct] = (f32x4){0.f, 0.f, 0.f, 0.f};

        int ar = (h * 64 + wave * 16 + lm) * C_IN;
#pragma unroll
        for (int ch = 0; ch < 6; ++ch) {
            int k0 = ch * 32 + quad * 8;
            short8 aH = *(const short8*)(QH + ar + k0);
            short8 aM = *(const short8*)(QM + ar + k0);
            short8 aL = *(const short8*)(QL + ar + k0);
            short8 bH[4], bM[4], bL[4];
#pragma unroll
            for (int ct = 0; ct < 4; ++ct) {
                int kr = (h * 64 + ct * 16 + lm) * C_IN + k0;
                bH[ct] = *(const short8*)(KH + kr);
                bM[ct] = *(const short8*)(KM + kr);
                bL[ct] = *(const short8*)(KL + kr);
            }
#pragma unroll
            for (int ct = 0; ct < 4; ++ct) {
                sacc[ct] = __builtin_amdgcn_mfma_f32_16x16x32_bf16(aH, bH[ct], sacc[ct], 0, 0, 0);
                sacc[ct] = __builtin_amdgcn_mfma_f32_16x16x32_bf16(aH, bM[ct], sacc[ct], 0, 0, 0);
                sacc[ct] = __builtin_amdgcn_mfma_f32_16x16x32_bf16(aM, bH[ct], sacc[ct], 0, 0, 0);
                sacc[ct] = __builtin_amdgcn_mfma_f32_16x16x32_bf16(aH, bL[ct], sacc[ct], 0, 0, 0);
                sacc[ct] = __builtin_amdgcn_mfma_f32_16x16x32_bf16(aM, bM[ct], sacc[ct], 0, 0, 0);
                sacc[ct] = __builtin_amdgcn_mfma_f32_16x16x32_bf16(aL, bH[ct], sacc[ct], 0, 0, 0);
            }
        }

#pragma unroll
        for (int r = 0; r < 4; ++r) {
            float s0 = sacc[0][r] * ATT_SCALE;
            float s1 = sacc[1][r] * ATT_SCALE;
            float s2 = sacc[2][r] * ATT_SCALE;
            float s3 = sacc[3][r] * ATT_SCALE;
            float mx = fmaxf(fmaxf(s0, s1), fmaxf(s2, s3));
            mx = fmaxf(mx, __shfl_xor(mx, 1));
            mx = fmaxf(mx, __shfl_xor(mx, 2));
            mx = fmaxf(mx, __shfl_xor(mx, 4));
            mx = fmaxf(mx, __shfl_xor(mx, 8));
            float e0 = __expf(s0 - mx), e1 = __expf(s1 - mx);
            float e2 = __expf(s2 - mx), e3 = __expf(s3 - mx);
            float sum = (e0 + e1) + (e2 + e3);
            sum += __shfl_xor(sum, 1);
            sum += __shfl_xor(sum, 2);
            sum += __shfl_xor(sum, 4);
            sum += __shfl_xor(sum, 8);
            float inv = 1.0f / sum;
            int i = wave * 16 + quad * 4 + r;
            At[lm * 68 + i]        = e0 * inv;
            At[(16 + lm) * 68 + i] = e1 * inv;
            At[(32 + lm) * 68 + i] = e2 * inv;
            At[(48 + lm) * 68 + i] = e3 * inv;
        }
        __syncthreads();

        f32x4 zacc[3][4];
#pragma unroll
        for (int mt = 0; mt < 3; ++mt)
#pragma unroll
            for (int ct = 0; ct < 4; ++ct) zacc[mt][ct] = (f32x4){0.f, 0.f, 0.f, 0.f};

#pragma unroll
        for (int ch = 0; ch < 2; ++ch) {
            int k0 = ch * 32 + quad * 8;
            short8 bH[4], bL[4];
#pragma unroll
            for (int ct = 0; ct < 4; ++ct) {
                float av[8];
                *(float4*)&av[0] = *(const float4*)&At[(ct * 16 + lm) * 68 + k0];
                *(float4*)&av[4] = *(const float4*)&At[(ct * 16 + lm) * 68 + k0 + 4];
#pragma unroll
                for (int j = 0; j < 8; ++j) {
                    unsigned short hh, ll;
                    split_bf(av[j], hh, ll);
                    bH[ct][j] = (short)hh; bL[ct][j] = (short)ll;
                }
            }
#pragma unroll
            for (int mt = 0; mt < 3; ++mt) {
                int orow = (wave * 48 + mt * 16 + lm) * 512 + h * 64 + k0;
                short8 aH = *(const short8*)(WOHp + orow);
                short8 aL = *(const short8*)(WOLp + orow);
#pragma unroll
                for (int ct = 0; ct < 4; ++ct) {
                    zacc[mt][ct] = __builtin_amdgcn_mfma_f32_16x16x32_bf16(aH, bH[ct], zacc[mt][ct], 0, 0, 0);
                    zacc[mt][ct] = __builtin_amdgcn_mfma_f32_16x16x32_bf16(aH, bL[ct], zacc[mt][ct], 0, 0, 0);
                    zacc[mt][ct] = __builtin_amdgcn_mfma_f32_16x16x32_bf16(aL, bH[ct], zacc[mt][ct], 0, 0, 0);
                }
            }
        }

        unsigned short* ZHb = (unsigned short*)(ws + ZH_OFF) + (size_t)b * ZEL;
        unsigned short* ZLb = (unsigned short*)(ws + ZL_OFF) + (size_t)b * ZEL;
#pragma unroll
        for (int mt = 0; mt < 3; ++mt)
#pragma unroll
            for (int r = 0; r < 4; ++r) {
                int o = wave * 48 + mt * 16 + quad * 4 + r;
#pragma unroll
                for (int ct = 0; ct < 4; ++ct) {
                    unsigned short hh, ll;
                    split_bf(zacc[mt][ct][r], hh, ll);
                    int idx = o * 512 + h * 64 + ct * 16 + lm;
                    ZHb[idx] = hh;
                    ZLb[idx] = ll;
                }
            }
    }
    gbar(bars + 3 * BAR_STRIDE);

    // ======== Phase D: wmix partials, K split 8 ways ========
    if (bid < 32) {
        int b = bid & 1, half = (bid >> 1) & 1, kseg = bid >> 2;

        const unsigned short* ZHb = (const unsigned short*)(ws + ZH_OFF) + (size_t)b * ZEL;
        const unsigned short* ZLb = (const unsigned short*)(ws + ZL_OFF) + (size_t)b * ZEL;
        const unsigned short* VTH = (const unsigned short*)(ws + WVTH_OFF);
        const unsigned short* VTL = (const unsigned short*)(ws + WVTL_OFF);

        f32x4 acc[3][6];
#pragma unroll
        for (int mt = 0; mt < 3; ++mt)
#pragma unroll
            for (int ct = 0; ct < 6; ++ct) acc[mt][ct] = (f32x4){0.f, 0.f, 0.f, 0.f};

        int rbase = wave * 48;
#pragma unroll
        for (int ch = 0; ch < 2; ++ch) {
            int k0 = kseg * 64 + ch * 32 + quad * 8;
            short8 aH[3], aL[3];
#pragma unroll
            for (int mt = 0; mt < 3; ++mt) {
                int o = (rbase + mt * 16 + lm) * 512 + k0;
                aH[mt] = *(const short8*)(ZHb + o);
                aL[mt] = *(const short8*)(ZLb + o);
            }
            short8 bH[6], bL[6];
#pragma unroll
            for (int ct = 0; ct < 6; ++ct) {
                int c = (half * 96 + ct * 16 + lm) * 512 + k0;
                bH[ct] = *(const short8*)(VTH + c);
                bL[ct] = *(const short8*)(VTL + c);
            }
#pragma unroll
            for (int ct = 0; ct < 6; ++ct)
#pragma unroll
                for (int mt = 0; mt < 3; ++mt) {
                    acc[mt][ct] = __builtin_amdgcn_mfma_f32_16x16x32_bf16(aH[mt], bH[ct], acc[mt][ct], 0, 0, 0);
                    acc[mt][ct] = __builtin_amdgcn_mfma_f32_16x16x32_bf16(aH[mt], bL[ct], acc[mt][ct], 0, 0, 0);
                    acc[mt][ct] = __builtin_amdgcn_mfma_f32_16x16x32_bf16(aL[mt], bH[ct], acc[mt][ct], 0, 0, 0);
                }
        }

        float* Pp = ws + WMX_OFF + (size_t)(kseg * NB + b) * GEL;
#pragma unroll
        for (int mt = 0; mt < 3; ++mt)
#pragma unroll
            for (int r = 0; r < 4; ++r) {
                int row = rbase + mt * 16 + quad * 4 + r;
#pragma unroll
                for (int ct = 0; ct < 6; ++ct)
                    Pp[row * C_IN + half * 96 + ct * 16 + lm] = acc[mt][ct][r];
            }
    }
    gbar(bars + 4 * BAR_STRIDE);

    // ======== Phase E: sum 8 K-partials, pack W to bf16 ========
    {
        int gid = bid * 256 + tid;
        if (gid < NB * (GEL / 4)) {
            int b = gid / (GEL / 4);
            int i4 = (gid - b * (GEL / 4)) * 4;
            const float* Pp = ws + WMX_OFF + (size_t)b * GEL + i4;
            float4 s = {0.f, 0.f, 0.f, 0.f};
#pragma unroll
            for (int ks = 0; ks < 8; ++ks) {
                float4 v = *(const float4*)(Pp + (size_t)ks * NB * GEL);
                s.x += v.x; s.y += v.y; s.z += v.z; s.w += v.w;
            }
            unsigned short o[4];
            o[0] = f2bf(s.x); o[1] = f2bf(s.y); o[2] = f2bf(s.z); o[3] = f2bf(s.w);
            *(unsigned long long*)((unsigned short*)(ws + WBF_OFF) + (size_t)b * GEL + i4) = pack4(o);
        }
    }
}

// ---------------- Gram fallback (fp32 atomic; used only if ws too small) ----------------
__global__ __launch_bounds__(512, 2) void gram_atomic(const float* __restrict__ x,
                                                      float* __restrict__ G) {
    int b     = blockIdx.y;
    int kbase = blockIdx.x * (GR_CH * GR_BK);

    __shared__ float Ls[GR_BK][196];

    int tid = threadIdx.x;
    int tx  = tid & 15;
    int tyy = tid >> 4;

    const float* xb = x + (size_t)b * C_IN * S_TOT;

    int lc[3], lkq[3];
#pragma unroll
    for (int q = 0; q < 3; q++) { int id = tid + 512 * q; lc[q] = id >> 3; lkq[q] = id & 7; }

    float acc[6][12] = {};
    float4 pf[3];

#pragma unroll
    for (int q = 0; q < 3; q++)
        pf[q] = *(const float4*)(xb + (size_t)lc[q] * S_TOT + kbase + lkq[q] * 4);

    for (int ch = 0; ch < GR_CH; ++ch) {
        __syncthreads();
#pragma unroll
        for (int q = 0; q < 3; q++) {
            Ls[lkq[q] * 4 + 0][lc[q]] = pf[q].x;
            Ls[lkq[q] * 4 + 1][lc[q]] = pf[q].y;
            Ls[lkq[q] * 4 + 2][lc[q]] = pf[q].z;
            Ls[lkq[q] * 4 + 3][lc[q]] = pf[q].w;
        }
        __syncthreads();
        if (ch + 1 < GR_CH) {
            int k0 = kbase + (ch + 1) * GR_BK;
#pragma unroll
            for (int q = 0; q < 3; q++)
                pf[q] = *(const float4*)(xb + (size_t)lc[q] * S_TOT + k0 + lkq[q] * 4);
        }
#pragma unroll
        for (int kk = 0; kk < GR_BK; ++kk) {
            float a[6], bb[12];
#pragma unroll
            for (int rr = 0; rr < 6; ++rr)  a[rr] = Ls[kk][tyy + 32 * rr];
#pragma unroll
            for (int cc = 0; cc < 12; ++cc) bb[cc] = Ls[kk][tx + 16 * cc];
#pragma unroll
            for (int rr = 0; rr < 6; ++rr)
#pragma unroll
                for (int cc = 0; cc < 12; ++cc)
                    acc[rr][cc] = fmaf(a[rr], bb[cc], acc[rr][cc]);
        }
    }

    float* Gb = G + b * C_IN * C_IN;
#pragma unroll
    for (int rr = 0; rr < 6; ++rr)
#pragma unroll
        for (int cc = 0; cc < 12; ++cc)
            atomicAdd(&Gb[(tyy + 32 * rr) * C_IN + tx + 16 * cc], acc[rr][cc]);
}

// ---------------- generic 64x64-tile GEMM (fp32 out; fallback path) ----------------
__global__ __launch_bounds__(256) void gemm64_kernel(const float* __restrict__ A,
                                                     const float* __restrict__ B,
                                                     float* __restrict__ C,
                                                     int K, int N,
                                                     long aStride, long bStride, long cStride) {
    int mi0 = blockIdx.x * 64;
    int nj0 = blockIdx.y * 64;
    int b   = blockIdx.z;

    __shared__ float As[16][68];
    __shared__ float Bs[16][68];

    int tid = threadIdx.x;
    int tx = tid & 15, ty = tid >> 4;
    int lrow = tid >> 2, lk = (tid & 3) * 4;
    int ldk = tid >> 4, ldn = (tid & 15) * 4;

    const float* Ab = A + b * aStride;
    const float* Bb = B + b * bStride;

    float acc[4][4] = {};

    for (int k0 = 0; k0 < K; k0 += 16) {
        float4 av = *(const float4*)(Ab + (size_t)(mi0 + lrow) * K + k0 + lk);
        float4 bv = *(const float4*)(Bb + (size_t)(k0 + ldk) * N + nj0 + ldn);
        __syncthreads();
        As[lk + 0][lrow] = av.x; As[lk + 1][lrow] = av.y;
        As[lk + 2][lrow] = av.z; As[lk + 3][lrow] = av.w;
        *(float4*)&Bs[ldk][ldn] = bv;
        __syncthreads();
#pragma unroll
        for (int kk = 0; kk < 16; kk++) {
            float4 a = *(const float4*)&As[kk][ty * 4];
            float4 bb = *(const float4*)&Bs[kk][tx * 4];
            acc[0][0] += a.x * bb.x; acc[0][1] += a.x * bb.y; acc[0][2] += a.x * bb.z; acc[0][3] += a.x * bb.w;
            acc[1][0] += a.y * bb.x; acc[1][1] += a.y * bb.y; acc[1][2] += a.y * bb.z; acc[1][3] += a.y * bb.w;
            acc[2][0] += a.z * bb.x; acc[2][1] += a.z * bb.y; acc[2][2] += a.z * bb.z; acc[2][3] += a.z * bb.w;
            acc[3][0] += a.w * bb.x; acc[3][1] += a.w * bb.y; acc[3][2] += a.w * bb.z; acc[3][3] += a.w * bb.w;
        }
    }

    float* Cb = C + b * cStride;
#pragma unroll
    for (int r = 0; r < 4; r++) {
        float4 v = { acc[r][0], acc[r][1], acc[r][2], acc[r][3] };
        *(float4*)(Cb + (size_t)(mi0 + ty * 4 + r) * N + nj0 + tx * 4) = v;
    }
}

// ---------------- same GEMM, bf16 packed output (fallback path) ----------------
__global__ __launch_bounds__(256) void gemm64bf_kernel(const float* __restrict__ A,
                                                       const float* __restrict__ B,
                                                       unsigned short* __restrict__ C,
                                                       int K, int N,
                                                       long aStride, long bStride, long cStride) {
    int mi0 = blockIdx.x * 64;
    int nj0 = blockIdx.y * 64;
    int b   = blockIdx.z;

    __shared__ float As[16][68];
    __shared__ float Bs[16][68];

    int tid = threadIdx.x;
    int tx = tid & 15, ty = tid >> 4;
    int lrow = tid >> 2, lk = (tid & 3) * 4;
    int ldk = tid >> 4, ldn = (tid & 15) * 4;

    const float* Ab = A + b * aStride;
    const float* Bb = B + b * bStride;

    float acc[4][4] = {};

    for (int k0 = 0; k0 < K; k0 += 16) {
        float4 av = *(const float4*)(Ab + (size_t)(mi0 + lrow) * K + k0 + lk);
        float4 bv = *(const float4*)(Bb + (size_t)(k0 + ldk) * N + nj0 + ldn);
        __syncthreads();
        As[lk + 0][lrow] = av.x; As[lk + 1][lrow] = av.y;
        As[lk + 2][lrow] = av.z; As[lk + 3][lrow] = av.w;
        *(float4*)&Bs[ldk][ldn] = bv;
        __syncthreads();
#pragma unroll
        for (int kk = 0; kk < 16; kk++) {
            float4 a = *(const float4*)&As[kk][ty * 4];
            float4 bb = *(const float4*)&Bs[kk][tx * 4];
            acc[0][0] += a.x * bb.x; acc[0][1] += a.x * bb.y; acc[0][2] += a.x * bb.z; acc[0][3] += a.x * bb.w;
            acc[1][0] += a.y * bb.x; acc[1][1] += a.y * bb.y; acc[1][2] += a.y * bb.z; acc[1][3] += a.y * bb.w;
            acc[2][0] += a.z * bb.x; acc[2][1] += a.z * bb.y; acc[2][2] += a.z * bb.z; acc[2][3] += a.z * bb.w;
            acc[3][0] += a.w * bb.x; acc[3][1] += a.w * bb.y; acc[3][2] += a.w * bb.z; acc[3][3] += a.w * bb.w;
        }
    }

    unsigned short* Cb = C + b * cStride;
#pragma unroll
    for (int r = 0; r < 4; r++) {
        union { unsigned long long q; unsigned int u[2]; } pk;
        pk.u[0] = pk_bf16(acc[r][0], acc[r][1]);
        pk.u[1] = pk_bf16(acc[r][2], acc[r][3]);
        *(unsigned long long*)&Cb[(size_t)(mi0 + ty * 4 + r) * N + nj0 + tx * 4] = pk.q;
    }
}

// ---------------- fallback fused sim/softmax/M ----------------
__global__ __launch_bounds__(256) void simsoftm_kernel(const float* __restrict__ T,
                                                       const float* __restrict__ wk,
                                                       const float* __restrict__ wv,
                                                       float* __restrict__ M) {
    int b = blockIdx.x, h = blockIdx.y;

    __shared__ float As[16][68];
    __shared__ float Bs[16][68];
    __shared__ float At[64][68];

    int tid = threadIdx.x;
    int tx = tid & 15, ty = tid >> 4;
    int ldk = tid >> 4, ldn = (tid & 15) * 4;
    int lrow = tid >> 2, lk = (tid & 3) * 4;

    const float* Th  = T + (size_t)b * 512 * C_IN + (size_t)(h * 64) * C_IN;
    const float* wkh = wk + (size_t)(h * 64) * C_IN;
    const float* wvh = wv + (size_t)(h * 64) * C_IN;

    float acc[4][4] = {};
    for (int k0 = 0; k0 < C_IN; k0 += 16) {
        float4 av = *(const float4*)(Th  + (size_t)lrow * C_IN + k0 + lk);
        float4 bv = *(const float4*)(wkh + (size_t)lrow * C_IN + k0 + lk);
        __syncthreads();
        As[lk + 0][lrow] = av.x; As[lk + 1][lrow] = av.y;
        As[lk + 2][lrow] = av.z; As[lk + 3][lrow] = av.w;
        Bs[lk + 0][lrow] = bv.x; Bs[lk + 1][lrow] = bv.y;
        Bs[lk + 2][lrow] = bv.z; Bs[lk + 3][lrow] = bv.w;
        __syncthreads();
#pragma unroll
        for (int kk = 0; kk < 16; kk++) {
            float4 a = *(const float4*)&As[kk][ty * 4];
            float4 bb = *(const float4*)&Bs[kk][tx * 4];
            acc[0][0] += a.x * bb.x; acc[0][1] += a.x * bb.y; acc[0][2] += a.x * bb.z; acc[0][3] += a.x * bb.w;
            acc[1][0] += a.y * bb.x; acc[1][1] += a.y * bb.y; acc[1][2] += a.y * bb.z; acc[1][3] += a.y * bb.w;
            acc[2][0] += a.z * bb.x; acc[2][1] += a.z * bb.y; acc[2][2] += a.z * bb.z; acc[2][3] += a.z * bb.w;
            acc[3][0] += a.w * bb.x; acc[3][1] += a.w * bb.y; acc[3][2] += a.w * bb.z; acc[3][3] += a.w * bb.w;
        }
    }

#pragma unroll
    for (int r = 0; r < 4; r++) {
        float s0 = acc[r][0] * ATT_SCALE, s1 = acc[r][1] * ATT_SCALE;
        float s2 = acc[r][2] * ATT_SCALE, s3 = acc[r][3] * ATT_SCALE;
        float mx = fmaxf(fmaxf(s0, s1), fmaxf(s2, s3));
        mx = fmaxf(mx, __shfl_xor(mx, 1));
        mx = fmaxf(mx, __shfl_xor(mx, 2));
        mx = fmaxf(mx, __shfl_xor(mx, 4));
        mx = fmaxf(mx, __shfl_xor(mx, 8));
        float e0 = __expf(s0 - mx), e1 = __expf(s1 - mx);
        float e2 = __expf(s2 - mx), e3 = __expf(s3 - mx);
        float sum = (e0 + e1) + (e2 + e3);
        sum += __shfl_xor(sum, 1);
        sum += __shfl_xor(sum, 2);
        sum += __shfl_xor(sum, 4);
        sum += __shfl_xor(sum, 8);
        float inv = 1.0f / sum;
        At[tx * 4 + 0][ty * 4 + r] = e0 * inv;
        At[tx * 4 + 1][ty * 4 + r] = e1 * inv;
        At[tx * 4 + 2][ty * 4 + r] = e2 * inv;
        At[tx * 4 + 3][ty * 4 + r] = e3 * inv;
    }

    float* Mb = M + (size_t)b * 512 * C_IN + (size_t)(h * 64) * C_IN;
    for (int nj = 0; nj < C_IN; nj += 64) {
        float acc2[4][4] = {};
        for (int j0 = 0; j0 < 64; j0 += 16) {
            float4 bv = *(const float4*)(wvh + (size_t)(j0 + ldk) * C_IN + nj + ldn);
            __syncthreads();
            *(float4*)&Bs[ldk][ldn] = bv;
            __syncthreads();
#pragma unroll
            for (int kk = 0; kk < 16; kk++) {
                float4 a = *(const float4*)&At[j0 + kk][ty * 4];
                float4 bb = *(const float4*)&Bs[kk][tx * 4];
                acc2[0][0] += a.x * bb.x; acc2[0][1] += a.x * bb.y; acc2[0][2] += a.x * bb.z; acc2[0][3] += a.x * bb.w;
                acc2[1][0] += a.y * bb.x; acc2[1][1] += a.y * bb.y; acc2[1][2] += a.y * bb.z; acc2[1][3] += a.y * bb.w;
                acc2[2][0] += a.z * bb.x; acc2[2][1] += a.z * bb.y; acc2[2][2] += a.z * bb.z; acc2[2][3] += a.z * bb.w;
                acc2[3][0] += a.w * bb.x; acc2[3][1] += a.w * bb.y; acc2[3][2] += a.w * bb.z; acc2[3][3] += a.w * bb.w;
            }
        }
#pragma unroll
        for (int r = 0; r < 4; r++) {
            float4 v = { acc2[r][0], acc2[r][1], acc2[r][2], acc2[r][3] };
            *(float4*)(Mb + (size_t)(ty * 4 + r) * C_IN + nj + tx * 4) = v;
        }
    }
}

// ---------------- out = W*x + bo, bf16 MFMA. grid (256, NB), block 256 (4 waves) ----------------
__global__ __launch_bounds__(256) void final_kernel(const float* __restrict__ x,
                                                    const unsigned short* __restrict__ Wbf,
                                                    const float* __restrict__ bo,
                                                    float* __restrict__ out) {
    int n0 = blockIdx.x * 128;
    int b  = blockIdx.y;

    __shared__ unsigned short Xs[128 * 40];

    int tid  = threadIdx.x;
    int wave = tid >> 6;
    int lane = tid & 63;
    int wm   = (wave & 1) * 96;
    int wn   = (wave >> 1) * 64;
    int lm   = lane & 15, quad = lane >> 4;

    int sn  = tid & 127;
    int skh = (tid >> 7) * 16;

    const float* xsrc = x + (size_t)b * C_IN * S_TOT + n0 + sn;
    const unsigned short* Wb = Wbf + b * C_IN * C_IN;

    f32x4 acc[6][4];
#pragma unroll
    for (int mt = 0; mt < 6; mt++)
#pragma unroll
        for (int nt = 0; nt < 4; nt++) acc[mt][nt] = (f32x4){0.f, 0.f, 0.f, 0.f};

    float pf[16];
#pragma unroll
    for (int j = 0; j < 16; j++) pf[j] = xsrc[(size_t)(skh + j) * S_TOT];

    for (int kc = 0; kc < 6; ++kc) {
        int k0 = kc * 32;
        __syncthreads();
        {
            union { uint4 q; unsigned int u[4]; } pk0, pk1;
#pragma unroll
            for (int j = 0; j < 4; j++) {
                pk0.u[j] = pk_bf16(pf[2 * j],     pf[2 * j + 1]);
                pk1.u[j] = pk_bf16(pf[8 + 2 * j], pf[8 + 2 * j + 1]);
            }
            *(uint4*)&Xs[sn * 40 + skh + 0] = pk0.q;
            *(uint4*)&Xs[sn * 40 + skh + 8] = pk1.q;
        }
        __syncthreads();
        if (kc + 1 < 6) {
            int kn = k0 + 32;
#pragma unroll
            for (int j = 0; j < 16; j++) pf[j] = xsrc[(size_t)(kn + skh + j) * S_TOT];
        }

        short8 afr[6];
#pragma unroll
        for (int mt = 0; mt < 6; mt++)
            afr[mt] = *(const short8*)(Wb + (size_t)(wm + mt * 16 + lm) * C_IN + k0 + quad * 8);
#pragma unroll
        for (int nt = 0; nt < 4; nt++) {
            short8 bfr = *(const short8*)&Xs[(wn + nt * 16 + lm) * 40 + quad * 8];
#pragma unroll
            for (int mt = 0; mt < 6; mt++)
                acc[mt][nt] = __builtin_amdgcn_mfma_f32_16x16x32_bf16(afr[mt], bfr, acc[mt][nt], 0, 0, 0);
        }
    }

#pragma unroll
    for (int mt = 0; mt < 6; mt++) {
#pragma unroll
        for (int r = 0; r < 4; r++) {
            int m = wm + mt * 16 + quad * 4 + r;
            float bias = bo[m];
            float* op = out + ((size_t)b * C_IN + m) * S_TOT + n0;
#pragma unroll
            for (int nt = 0; nt < 4; nt++)
                op[wn + nt * 16 + lm] = acc[mt][nt][r] + bias;
        }
    }
}

extern "C" void kernel_launch(void* const* d_in, const int* in_sizes, int n_in,
                              void* d_out, int out_size, void* d_ws, size_t ws_size,
                              hipStream_t stream) {
    const float* x  = (const float*)d_in[0];
    const float* wq = (const float*)d_in[1];
    const float* wk = (const float*)d_in[2];
    const float* wv = (const float*)d_in[3];
    const float* wo = (const float*)d_in[4];
    const float* bo = (const float*)d_in[5];
    float* out = (float*)d_out;
    float* ws  = (float*)d_ws;

    unsigned short* gWbf = (unsigned short*)(ws + WBF_OFF);

    bool bigws = ws_size >= (size_t)WS_END * sizeof(float);
    if (bigws) {
        // 3 dispatches: gram(+weight split, zeroes barrier) -> middle (store/poll grid barrier) -> final
        gram_partial<<<dim3(NSLICE, NB), 512, 0, stream>>>(x, wq, wk, wv, wo, ws);
        mega_mid<<<dim3(MEGA_NBLK), 256, 0, stream>>>(ws);
        final_kernel<<<dim3(256, NB), 256, 0, stream>>>(x, gWbf, bo, out);
    } else {
        // fallback: original proven chain
        float* gG = ws + G_OFF;
        float* gT = ws + T_OFF;
        float* gM = ws + M_OFF;
        hipMemsetAsync(gG, 0, G_SZ * sizeof(float), stream);
        gram_atomic<<<dim3(NSLICE, NB), 512, 0, stream>>>(x, gG);
        gemm64_kernel<<<dim3(8, 3, NB), 256, 0, stream>>>(
            wq, gG, gT, C_IN, C_IN, 0L, (long)(C_IN * C_IN), (long)(512 * C_IN));
        simsoftm_kernel<<<dim3(NB, NH), 256, 0, stream>>>(gT, wk, wv, gM);
        gemm64bf_kernel<<<dim3(3, 3, NB), 256, 0, stream>>>(
            wo, gM, gWbf, 512, C_IN, 0L, (long)(512 * C_IN), (long)(C_IN * C_IN));
        final_kernel<<<dim3(256, NB), 256, 0, stream>>>(x, gWbf, bo, out);
    }
}

// Round 8
// 221.006 us; speedup vs baseline: 1.5690x; 1.5690x over previous
//
#include <hip/hip_runtime.h>
#include <hip/hip_bf16.h>

#define S_TOT 32768
#define C_IN 192
#define NB 2
#define NH 8
#define DH 64
#define ATT_SCALE 0.125f
#define NSLICE 128
#define GR_CH 8
#define GR_BK 32

// ---------------- workspace layout (float units) ----------------
#define G_OFF   0
#define G_SZ    (NB * C_IN * C_IN)
#define T_OFF   (G_OFF + G_SZ)
#define T_SZ    (NB * 512 * C_IN)
#define M_OFF   (T_OFF + T_SZ)
#define M_SZ    (NB * 512 * C_IN)
#define WBF_OFF (M_OFF + M_SZ)
#define WBF_SZ  (NB * C_IN * C_IN / 2)
#define P_OFF   (WBF_OFF + WBF_SZ)
#define P_SZ    (NB * NSLICE * C_IN * C_IN)

// split-weight / split-G / split-Z storage (each array = N ushorts = N/2 floats)
#define WEL      (512 * C_IN)
#define SPL_FL   (WEL / 2)
#define WQH_OFF  (P_OFF + P_SZ)
#define WQM_OFF  (WQH_OFF + SPL_FL)
#define WQL_OFF  (WQM_OFF + SPL_FL)
#define WKH_OFF  (WQL_OFF + SPL_FL)
#define WKM_OFF  (WKH_OFF + SPL_FL)
#define WKL_OFF  (WKM_OFF + SPL_FL)
#define WOH_OFF  (WKL_OFF + SPL_FL)
#define WOL_OFF  (WOH_OFF + SPL_FL)
#define WVTH_OFF (WOL_OFF + SPL_FL)
#define WVTL_OFF (WVTH_OFF + SPL_FL)
#define GEL      (C_IN * C_IN)
#define GH_OFF   (WVTL_OFF + SPL_FL)
#define GM_OFF   (GH_OFF + NB * GEL / 2)
#define GL_OFF   (GM_OFF + NB * GEL / 2)
#define ZEL      (C_IN * 512)
#define ZH_OFF   (GL_OFF + NB * GEL / 2)
#define ZL_OFF   (ZH_OFF + NB * ZEL / 2)

// barrier state: 2 instances x 32 uints {counter @+0, flag @+16}
#define BAR_OFF  (ZL_OFF + NB * ZEL / 2)
#define BAR_SZ   64
#define WS_END   (BAR_OFF + BAR_SZ)

#define MEGA_NBLK 36    // 36 x 256 thr = 9216 = GEL/4 exactly (phase A: 1 float4/thread/batch)
#define BC_NBLK   16    // phase B+C blocks (b,h)
#define D_NBLK    8     // phase D blocks (b,half,cw)

typedef __attribute__((ext_vector_type(8))) short short8;
typedef __attribute__((ext_vector_type(4))) float f32x4;

__device__ inline unsigned short f2bf(float f) {   // RNE
    unsigned int u = __float_as_uint(f);
    u += 0x7fffu + ((u >> 16) & 1u);
    return (unsigned short)(u >> 16);
}

__device__ inline unsigned int pk_bf16(float a, float b) {  // packed RNE pair
    __hip_bfloat162 t = __float22bfloat162_rn(make_float2(a, b));
    unsigned int bits;
    __builtin_memcpy(&bits, &t, 4);
    return bits;
}

__device__ inline void split_bf(float v, unsigned short& h, unsigned short& l) {
    unsigned int u = __float_as_uint(v);
    h = (unsigned short)(u >> 16);
    float hf = __uint_as_float(u & 0xffff0000u);
    l = f2bf(v - hf);
}

__device__ inline void split3_bf(float v, unsigned short& h, unsigned short& m, unsigned short& l) {
    unsigned int u = __float_as_uint(v);
    h = (unsigned short)(u >> 16);
    float hf = __uint_as_float(u & 0xffff0000u);
    float r1 = v - hf;
    unsigned int u1 = __float_as_uint(r1);
    m = (unsigned short)(u1 >> 16);
    float mf = __uint_as_float(u1 & 0xffff0000u);
    l = f2bf(r1 - mf);
}

__device__ inline unsigned long long pack4(const unsigned short* s) {
    return (unsigned long long)s[0] | ((unsigned long long)s[1] << 16)
         | ((unsigned long long)s[2] << 32) | ((unsigned long long)s[3] << 48);
}

// Software grid barrier. Cost model from rounds 4-7: ~0.2us PER BLOCK per
// barrier (device-scope fence traffic), independent of spin mechanism.
// Lever: small participant count. State zeroed by the PREVIOUS dispatch.
__device__ inline void gbar(unsigned int* bar, unsigned int count) {
    __syncthreads();
    if (threadIdx.x == 0) {
        __threadfence();  // release: this block's phase writes device-visible
        unsigned int prev = __hip_atomic_fetch_add(bar, 1u, __ATOMIC_ACQ_REL,
                                                   __HIP_MEMORY_SCOPE_AGENT);
        if (prev == count - 1u) {
            __hip_atomic_store(bar + 16, 1u, __ATOMIC_RELEASE, __HIP_MEMORY_SCOPE_AGENT);
        } else {
            while (__hip_atomic_load(bar + 16, __ATOMIC_ACQUIRE,
                                     __HIP_MEMORY_SCOPE_AGENT) == 0u)
                __builtin_amdgcn_s_sleep(2);
        }
    }
    __syncthreads();
    __threadfence();  // acquire: discard stale cached lines before reading
}

// One unit of weight pre-splitting; 98304 units over gram_partial's 256 blocks x 384 lanes.
__device__ inline void split_unit(int u, const float* wq, const float* wk,
                                  const float* wv, const float* wo, float* ws) {
    int region = u / 24576;
    int r = u - region * 24576;
    if (region < 3) {
        const float* src = (region == 0) ? wq : (region == 1) ? wk : wo;
        int i = r * 4;
        float4 v = *(const float4*)(src + i);
        if (region < 2) {
            unsigned short h[4], m[4], l[4];
            split3_bf(v.x, h[0], m[0], l[0]);
            split3_bf(v.y, h[1], m[1], l[1]);
            split3_bf(v.z, h[2], m[2], l[2]);
            split3_bf(v.w, h[3], m[3], l[3]);
            int base = (region == 0) ? WQH_OFF : WKH_OFF;
            *(unsigned long long*)((unsigned short*)(ws + base) + i)              = pack4(h);
            *(unsigned long long*)((unsigned short*)(ws + base + SPL_FL) + i)     = pack4(m);
            *(unsigned long long*)((unsigned short*)(ws + base + 2 * SPL_FL) + i) = pack4(l);
        } else {
            unsigned short h[4], l[4];
            split_bf(v.x, h[0], l[0]);
            split_bf(v.y, h[1], l[1]);
            split_bf(v.z, h[2], l[2]);
            split_bf(v.w, h[3], l[3]);
            *(unsigned long long*)((unsigned short*)(ws + WOH_OFF) + i) = pack4(h);
            *(unsigned long long*)((unsigned short*)(ws + WOL_OFF) + i) = pack4(l);
        }
    } else {
        int j4 = r / 192;
        int c  = r - j4 * 192;
        int j  = j4 * 4;
        unsigned short h[4], l[4];
#pragma unroll
        for (int jj = 0; jj < 4; ++jj)
            split_bf(wv[(size_t)(j + jj) * C_IN + c], h[jj], l[jj]);
        *(unsigned long long*)((unsigned short*)(ws + WVTH_OFF) + c * 512 + j) = pack4(h);
        *(unsigned long long*)((unsigned short*)(ws + WVTL_OFF) + c * 512 + j) = pack4(l);
    }
}

// ---------------- Gram via split-bf16 MFMA: P[b][slice] = X-slice * X-slice^T ----------------
__global__ __launch_bounds__(512, 2) void gram_partial(const float* __restrict__ x,
                                                       const float* __restrict__ wq,
                                                       const float* __restrict__ wk,
                                                       const float* __restrict__ wv,
                                                       const float* __restrict__ wo,
                                                       float* __restrict__ ws) {
    int b     = blockIdx.y;
    int slice = blockIdx.x;
    int kbase = slice * (GR_CH * GR_BK);

    __shared__ unsigned short Hs[192 * 40];
    __shared__ unsigned short Lo[192 * 40];

    int tid  = threadIdx.x;
    int wave = tid >> 6;
    int lane = tid & 63;
    int rw   = wave & 3;
    int cw   = wave >> 2;
    int lm   = lane & 15, quad = lane >> 4;

    // zero the mega_mid barrier state for this iteration (visible at next dispatch)
    if (blockIdx.x == 0 && blockIdx.y == 0 && tid < BAR_SZ)
        ((unsigned int*)(ws + BAR_OFF))[tid] = 0u;

    const float* xb = x + (size_t)b * C_IN * S_TOT;

    int lc[3], lkq[3];
#pragma unroll
    for (int q = 0; q < 3; q++) { int id = tid + 512 * q; lc[q] = id >> 3; lkq[q] = id & 7; }

    f32x4 acc[3][6];
#pragma unroll
    for (int mt = 0; mt < 3; mt++)
#pragma unroll
        for (int nt = 0; nt < 6; nt++) acc[mt][nt] = (f32x4){0.f, 0.f, 0.f, 0.f};

    float4 pf[3];
#pragma unroll
    for (int q = 0; q < 3; q++)
        pf[q] = *(const float4*)(xb + (size_t)lc[q] * S_TOT + kbase + lkq[q] * 4);

    if (tid < 384) split_unit((b * NSLICE + slice) * 384 + tid, wq, wk, wv, wo, ws);

    for (int ch = 0; ch < GR_CH; ++ch) {
        __syncthreads();
#pragma unroll
        for (int q = 0; q < 3; q++) {
            unsigned short h[4], l[4];
            split_bf(pf[q].x, h[0], l[0]);
            split_bf(pf[q].y, h[1], l[1]);
            split_bf(pf[q].z, h[2], l[2]);
            split_bf(pf[q].w, h[3], l[3]);
            *(unsigned long long*)&Hs[lc[q] * 40 + lkq[q] * 4] = pack4(h);
            *(unsigned long long*)&Lo[lc[q] * 40 + lkq[q] * 4] = pack4(l);
        }
        __syncthreads();
        if (ch + 1 < GR_CH) {
            int k0 = kbase + (ch + 1) * GR_BK;
#pragma unroll
            for (int q = 0; q < 3; q++)
                pf[q] = *(const float4*)(xb + (size_t)lc[q] * S_TOT + k0 + lkq[q] * 4);
        }

        short8 ah[3], al[3];
#pragma unroll
        for (int mt = 0; mt < 3; mt++) {
            int row = 48 * rw + mt * 16 + lm;
            ah[mt] = *(const short8*)&Hs[row * 40 + quad * 8];
            al[mt] = *(const short8*)&Lo[row * 40 + quad * 8];
        }
#pragma unroll
        for (int nt = 0; nt < 6; nt++) {
            int col = 96 * cw + nt * 16 + lm;
            short8 bh = *(const short8*)&Hs[col * 40 + quad * 8];
            short8 bl = *(const short8*)&Lo[col * 40 + quad * 8];
#pragma unroll
            for (int mt = 0; mt < 3; mt++) {
                acc[mt][nt] = __builtin_amdgcn_mfma_f32_16x16x32_bf16(ah[mt], bh, acc[mt][nt], 0, 0, 0);
                acc[mt][nt] = __builtin_amdgcn_mfma_f32_16x16x32_bf16(ah[mt], bl, acc[mt][nt], 0, 0, 0);
                acc[mt][nt] = __builtin_amdgcn_mfma_f32_16x16x32_bf16(al[mt], bh, acc[mt][nt], 0, 0, 0);
            }
        }
    }

    float* Pb = ws + P_OFF + ((size_t)(b * NSLICE + slice)) * (C_IN * C_IN);
#pragma unroll
    for (int mt = 0; mt < 3; mt++) {
#pragma unroll
        for (int r = 0; r < 4; r++) {
            int row = 48 * rw + mt * 16 + quad * 4 + r;
#pragma unroll
            for (int nt = 0; nt < 6; nt++)
                Pb[row * C_IN + 96 * cw + nt * 16 + lm] = acc[mt][nt][r];
        }
    }
}

// ---------------- middle, one dispatch, 36 blocks, 2 barriers ----------------
// A: P-reduce (all 36) -> [bar 36] -> B+C fused per (b,h) (16) -> [bar 16] -> D wmix (8)
__global__ __launch_bounds__(256) void mega_mid(float* __restrict__ ws) {
    unsigned int* bars = (unsigned int*)(ws + BAR_OFF);
    int bid  = blockIdx.x;
    int tid  = threadIdx.x;
    int wave = tid >> 6;
    int lane = tid & 63;
    int lm   = lane & 15, quad = lane >> 4;

    __shared__ float SQ[64 * 196];   // Qt fp32 [64][196]; later reused as attn^T [64][68]

    // ======== Phase A: each thread sums 128 slices for ONE float4 of G, per batch ========
    {
        int tidg = bid * 256 + tid;          // 0..9215 == GEL/4 exactly
        int idx4 = tidg * 4;
#pragma unroll 1
        for (int b = 0; b < NB; ++b) {
            const float* Pb = ws + P_OFF + (size_t)(b * NSLICE) * GEL + idx4;
            float4 acc = {0.f, 0.f, 0.f, 0.f};
#pragma unroll 1
            for (int t = 0; t < 8; ++t) {
                float4 v[16];
#pragma unroll
                for (int i = 0; i < 16; ++i)
                    v[i] = *(const float4*)(Pb + (size_t)(t * 16 + i) * GEL);
#pragma unroll
                for (int i = 0; i < 16; ++i) {
                    acc.x += v[i].x; acc.y += v[i].y; acc.z += v[i].z; acc.w += v[i].w;
                }
            }
            unsigned short h[4], m[4], l[4];
            split3_bf(acc.x, h[0], m[0], l[0]);
            split3_bf(acc.y, h[1], m[1], l[1]);
            split3_bf(acc.z, h[2], m[2], l[2]);
            split3_bf(acc.w, h[3], m[3], l[3]);
            *(unsigned long long*)((unsigned short*)(ws + GH_OFF) + (size_t)b * GEL + idx4) = pack4(h);
            *(unsigned long long*)((unsigned short*)(ws + GM_OFF) + (size_t)b * GEL + idx4) = pack4(m);
            *(unsigned long long*)((unsigned short*)(ws + GL_OFF) + (size_t)b * GEL + idx4) = pack4(l);
        }
    }
    gbar(bars + 0, MEGA_NBLK);
    if (bid >= BC_NBLK) return;

    // ======== Phase B+C fused per (b,h): Qt=Wq_h*G -> LDS -> sim -> softmax -> Z ========
    {
        int b = bid & 1, h = bid >> 1;

        const unsigned short* AH = (const unsigned short*)(ws + WQH_OFF);
        const unsigned short* AM = (const unsigned short*)(ws + WQM_OFF);
        const unsigned short* AL = (const unsigned short*)(ws + WQL_OFF);
        const unsigned short* GH = (const unsigned short*)(ws + GH_OFF) + (size_t)b * GEL;
        const unsigned short* GM = (const unsigned short*)(ws + GM_OFF) + (size_t)b * GEL;
        const unsigned short* GL = (const unsigned short*)(ws + GL_OFF) + (size_t)b * GEL;
        const unsigned short* KH = (const unsigned short*)(ws + WKH_OFF);
        const unsigned short* KM = (const unsigned short*)(ws + WKM_OFF);
        const unsigned short* KL = (const unsigned short*)(ws + WKL_OFF);
        const unsigned short* WOHp = (const unsigned short*)(ws + WOH_OFF);
        const unsigned short* WOLp = (const unsigned short*)(ws + WOL_OFF);

        // ---- B: Qt = Wq_h * G (64x192), 6-term triple MFMA, fp32 into LDS ----
        f32x4 qacc[12];
#pragma unroll
        for (int ct = 0; ct < 12; ++ct) qacc[ct] = (f32x4){0.f, 0.f, 0.f, 0.f};

        int qr = (h * 64 + wave * 16 + lm) * C_IN;
#pragma unroll
        for (int hf = 0; hf < 2; ++hf) {
#pragma unroll
            for (int ch = 0; ch < 6; ++ch) {
                int k0 = ch * 32 + quad * 8;
                short8 aH = *(const short8*)(AH + qr + k0);
                short8 aM = *(const short8*)(AM + qr + k0);
                short8 aL = *(const short8*)(AL + qr + k0);
                short8 bH[6], bM[6], bL[6];
#pragma unroll
                for (int ct = 0; ct < 6; ++ct) {
                    int gr = ((hf * 6 + ct) * 16 + lm) * C_IN + k0;
                    bH[ct] = *(const short8*)(GH + gr);
                    bM[ct] = *(const short8*)(GM + gr);
                    bL[ct] = *(const short8*)(GL + gr);
                }
#pragma unroll
                for (int ct = 0; ct < 6; ++ct) {
                    int q = hf * 6 + ct;
                    qacc[q] = __builtin_amdgcn_mfma_f32_16x16x32_bf16(aH, bH[ct], qacc[q], 0, 0, 0);
                    qacc[q] = __builtin_amdgcn_mfma_f32_16x16x32_bf16(aH, bM[ct], qacc[q], 0, 0, 0);
                    qacc[q] = __builtin_amdgcn_mfma_f32_16x16x32_bf16(aM, bH[ct], qacc[q], 0, 0, 0);
                    qacc[q] = __builtin_amdgcn_mfma_f32_16x16x32_bf16(aH, bL[ct], qacc[q], 0, 0, 0);
                    qacc[q] = __builtin_amdgcn_mfma_f32_16x16x32_bf16(aM, bM[ct], qacc[q], 0, 0, 0);
                    qacc[q] = __builtin_amdgcn_mfma_f32_16x16x32_bf16(aL, bH[ct], qacc[q], 0, 0, 0);
                }
            }
        }
#pragma unroll
        for (int ct = 0; ct < 12; ++ct)
#pragma unroll
            for (int r = 0; r < 4; ++r)
                SQ[(wave * 16 + quad * 4 + r) * 196 + ct * 16 + lm] = qacc[ct][r];
        __syncthreads();

        // ---- C1: sim = Qt * Wk_h^T (64x64), Qt triple-split on read ----
        f32x4 sacc[4];
#pragma unroll
        for (int ct = 0; ct < 4; ++ct) sacc[ct] = (f32x4){0.f, 0.f, 0.f, 0.f};
#pragma unroll
        for (int ch = 0; ch < 6; ++ch) {
            int k0 = ch * 32 + quad * 8;
            float qv[8];
            *(float4*)&qv[0] = *(const float4*)&SQ[(wave * 16 + lm) * 196 + k0];
            *(float4*)&qv[4] = *(const float4*)&SQ[(wave * 16 + lm) * 196 + k0 + 4];
            short8 aH, aM, aL;
#pragma unroll
            for (int j = 0; j < 8; ++j) {
                unsigned short hh, mm, ll;
                split3_bf(qv[j], hh, mm, ll);
                aH[j] = (short)hh; aM[j] = (short)mm; aL[j] = (short)ll;
            }
            short8 bH[4], bM[4], bL[4];
#pragma unroll
            for (int ct = 0; ct < 4; ++ct) {
                int kr = (h * 64 + ct * 16 + lm) * C_IN + k0;
                bH[ct] = *(const short8*)(KH + kr);
                bM[ct] = *(const short8*)(KM + kr);
                bL[ct] = *(const short8*)(KL + kr);
            }
#pragma unroll
            for (int ct = 0; ct < 4; ++ct) {
                sacc[ct] = __builtin_amdgcn_mfma_f32_16x16x32_bf16(aH, bH[ct], sacc[ct], 0, 0, 0);
                sacc[ct] = __builtin_amdgcn_mfma_f32_16x16x32_bf16(aH, bM[ct], sacc[ct], 0, 0, 0);
                sacc[ct] = __builtin_amdgcn_mfma_f32_16x16x32_bf16(aM, bH[ct], sacc[ct], 0, 0, 0);
                sacc[ct] = __builtin_amdgcn_mfma_f32_16x16x32_bf16(aH, bL[ct], sacc[ct], 0, 0, 0);
                sacc[ct] = __builtin_amdgcn_mfma_f32_16x16x32_bf16(aM, bM[ct], sacc[ct], 0, 0, 0);
                sacc[ct] = __builtin_amdgcn_mfma_f32_16x16x32_bf16(aL, bH[ct], sacc[ct], 0, 0, 0);
            }
        }
        __syncthreads();   // all Qt reads done before attn^T overwrites SQ

        // ---- softmax over j (cols), store attn^T into At[j][i] ----
        float* At = SQ;    // [64][68]
#pragma unroll
        for (int r = 0; r < 4; ++r) {
            float s0 = sacc[0][r] * ATT_SCALE;
            float s1 = sacc[1][r] * ATT_SCALE;
            float s2 = sacc[2][r] * ATT_SCALE;
            float s3 = sacc[3][r] * ATT_SCALE;
            float mx = fmaxf(fmaxf(s0, s1), fmaxf(s2, s3));
            mx = fmaxf(mx, __shfl_xor(mx, 1));
            mx = fmaxf(mx, __shfl_xor(mx, 2));
            mx = fmaxf(mx, __shfl_xor(mx, 4));
            mx = fmaxf(mx, __shfl_xor(mx, 8));
            float e0 = __expf(s0 - mx), e1 = __expf(s1 - mx);
            float e2 = __expf(s2 - mx), e3 = __expf(s3 - mx);
            float sum = (e0 + e1) + (e2 + e3);
            sum += __shfl_xor(sum, 1);
            sum += __shfl_xor(sum, 2);
            sum += __shfl_xor(sum, 4);
            sum += __shfl_xor(sum, 8);
            float inv = 1.0f / sum;
            int i = wave * 16 + quad * 4 + r;
            At[lm * 68 + i]        = e0 * inv;
            At[(16 + lm) * 68 + i] = e1 * inv;
            At[(32 + lm) * 68 + i] = e2 * inv;
            At[(48 + lm) * 68 + i] = e3 * inv;
        }
        __syncthreads();

        // ---- C2: Z_h = Wo[:, 64h:64h+64] * attn (192x64), double-split ----
        f32x4 zacc[3][4];
#pragma unroll
        for (int mt = 0; mt < 3; ++mt)
#pragma unroll
            for (int ct = 0; ct < 4; ++ct) zacc[mt][ct] = (f32x4){0.f, 0.f, 0.f, 0.f};

#pragma unroll
        for (int ch = 0; ch < 2; ++ch) {
            int k0 = ch * 32 + quad * 8;
            short8 bH[4], bL[4];
#pragma unroll
            for (int ct = 0; ct < 4; ++ct) {
                float av[8];
                *(float4*)&av[0] = *(const float4*)&At[(ct * 16 + lm) * 68 + k0];
                *(float4*)&av[4] = *(const float4*)&At[(ct * 16 + lm) * 68 + k0 + 4];
#pragma unroll
                for (int j = 0; j < 8; ++j) {
                    unsigned short hh, ll;
                    split_bf(av[j], hh, ll);
                    bH[ct][j] = (short)hh; bL[ct][j] = (short)ll;
                }
            }
#pragma unroll
            for (int mt = 0; mt < 3; ++mt) {
                int orow = (wave * 48 + mt * 16 + lm) * 512 + h * 64 + k0;
                short8 aH = *(const short8*)(WOHp + orow);
                short8 aL = *(const short8*)(WOLp + orow);
#pragma unroll
                for (int ct = 0; ct < 4; ++ct) {
                    zacc[mt][ct] = __builtin_amdgcn_mfma_f32_16x16x32_bf16(aH, bH[ct], zacc[mt][ct], 0, 0, 0);
                    zacc[mt][ct] = __builtin_amdgcn_mfma_f32_16x16x32_bf16(aH, bL[ct], zacc[mt][ct], 0, 0, 0);
                    zacc[mt][ct] = __builtin_amdgcn_mfma_f32_16x16x32_bf16(aL, bH[ct], zacc[mt][ct], 0, 0, 0);
                }
            }
        }

        unsigned short* ZHb = (unsigned short*)(ws + ZH_OFF) + (size_t)b * ZEL;
        unsigned short* ZLb = (unsigned short*)(ws + ZL_OFF) + (size_t)b * ZEL;
#pragma unroll
        for (int mt = 0; mt < 3; ++mt)
#pragma unroll
            for (int r = 0; r < 4; ++r) {
                int o = wave * 48 + mt * 16 + quad * 4 + r;
#pragma unroll
                for (int ct = 0; ct < 4; ++ct) {
                    unsigned short hh, ll;
                    split_bf(zacc[mt][ct][r], hh, ll);
                    int idx = o * 512 + h * 64 + ct * 16 + lm;
                    ZHb[idx] = hh;
                    ZLb[idx] = ll;
                }
            }
    }
    gbar(bars + 32, BC_NBLK);
    if (bid >= D_NBLK) return;

    // ======== Phase D: W = Z * Wv^T (full K=512), bf16 out. 8 blocks (b,half,cw) ========
    {
        int b = bid & 1, half = (bid >> 1) & 1, cwD = bid >> 2;
        int rw = wave;

        const unsigned short* ZHb = (const unsigned short*)(ws + ZH_OFF) + (size_t)b * ZEL;
        const unsigned short* ZLb = (const unsigned short*)(ws + ZL_OFF) + (size_t)b * ZEL;
        const unsigned short* VTH = (const unsigned short*)(ws + WVTH_OFF);
        const unsigned short* VTL = (const unsigned short*)(ws + WVTL_OFF);

        f32x4 acc[3][3];
#pragma unroll
        for (int mt = 0; mt < 3; ++mt)
#pragma unroll
            for (int ct = 0; ct < 3; ++ct) acc[mt][ct] = (f32x4){0.f, 0.f, 0.f, 0.f};

#define WMIX_LOAD(CH, AH_, AL_, BH_, BL_)                                     \
    do {                                                                      \
        int k0_ = (CH) * 32 + quad * 8;                                       \
        for (int mt_ = 0; mt_ < 3; ++mt_) {                                   \
            int o_ = (rw * 48 + mt_ * 16 + lm) * 512 + k0_;                   \
            AH_[mt_] = *(const short8*)(ZHb + o_);                            \
            AL_[mt_] = *(const short8*)(ZLb + o_);                            \
        }                                                                     \
        for (int ct_ = 0; ct_ < 3; ++ct_) {                                   \
            int c_ = (half * 96 + cwD * 48 + ct_ * 16 + lm) * 512 + k0_;      \
            BH_[ct_] = *(const short8*)(VTH + c_);                            \
            BL_[ct_] = *(const short8*)(VTL + c_);                            \
        }                                                                     \
    } while (0)

#define WMIX_MFMA(AH_, AL_, BH_, BL_)                                                           \
    do {                                                                                        \
        for (int ct_ = 0; ct_ < 3; ++ct_)                                                       \
            for (int mt_ = 0; mt_ < 3; ++mt_) {                                                 \
                acc[mt_][ct_] = __builtin_amdgcn_mfma_f32_16x16x32_bf16(AH_[mt_], BH_[ct_], acc[mt_][ct_], 0, 0, 0); \
                acc[mt_][ct_] = __builtin_amdgcn_mfma_f32_16x16x32_bf16(AH_[mt_], BL_[ct_], acc[mt_][ct_], 0, 0, 0); \
                acc[mt_][ct_] = __builtin_amdgcn_mfma_f32_16x16x32_bf16(AL_[mt_], BH_[ct_], acc[mt_][ct_], 0, 0, 0); \
            }                                                                                   \
    } while (0)

        short8 aH0[3], aL0[3], bH0[3], bL0[3];
        short8 aH1[3], aL1[3], bH1[3], bL1[3];
        WMIX_LOAD(0, aH0, aL0, bH0, bL0);
#pragma unroll
        for (int ch = 0; ch < 16; ch += 2) {
            WMIX_LOAD(ch + 1, aH1, aL1, bH1, bL1);
            WMIX_MFMA(aH0, aL0, bH0, bL0);
            if (ch + 2 < 16) WMIX_LOAD(ch + 2, aH0, aL0, bH0, bL0);
            WMIX_MFMA(aH1, aL1, bH1, bL1);
        }

        unsigned short* Wb = (unsigned short*)(ws + WBF_OFF) + (size_t)b * C_IN * C_IN;
#pragma unroll
        for (int mt = 0; mt < 3; ++mt)
#pragma unroll
            for (int r = 0; r < 4; ++r) {
                int m = rw * 48 + mt * 16 + quad * 4 + r;
#pragma unroll
                for (int ct = 0; ct < 3; ++ct)
                    Wb[m * C_IN + half * 96 + cwD * 48 + ct * 16 + lm] = f2bf(acc[mt][ct][r]);
            }
    }
}

// ---------------- Gram fallback (fp32 atomic; used only if ws too small) ----------------
__global__ __launch_bounds__(512, 2) void gram_atomic(const float* __restrict__ x,
                                                      float* __restrict__ G) {
    int b     = blockIdx.y;
    int kbase = blockIdx.x * (GR_CH * GR_BK);

    __shared__ float Ls[GR_BK][196];

    int tid = threadIdx.x;
    int tx  = tid & 15;
    int tyy = tid >> 4;

    const float* xb = x + (size_t)b * C_IN * S_TOT;

    int lc[3], lkq[3];
#pragma unroll
    for (int q = 0; q < 3; q++) { int id = tid + 512 * q; lc[q] = id >> 3; lkq[q] = id & 7; }

    float acc[6][12] = {};
    float4 pf[3];

#pragma unroll
    for (int q = 0; q < 3; q++)
        pf[q] = *(const float4*)(xb + (size_t)lc[q] * S_TOT + kbase + lkq[q] * 4);

    for (int ch = 0; ch < GR_CH; ++ch) {
        __syncthreads();
#pragma unroll
        for (int q = 0; q < 3; q++) {
            Ls[lkq[q] * 4 + 0][lc[q]] = pf[q].x;
            Ls[lkq[q] * 4 + 1][lc[q]] = pf[q].y;
            Ls[lkq[q] * 4 + 2][lc[q]] = pf[q].z;
            Ls[lkq[q] * 4 + 3][lc[q]] = pf[q].w;
        }
        __syncthreads();
        if (ch + 1 < GR_CH) {
            int k0 = kbase + (ch + 1) * GR_BK;
#pragma unroll
            for (int q = 0; q < 3; q++)
                pf[q] = *(const float4*)(xb + (size_t)lc[q] * S_TOT + k0 + lkq[q] * 4);
        }
#pragma unroll
        for (int kk = 0; kk < GR_BK; ++kk) {
            float a[6], bb[12];
#pragma unroll
            for (int rr = 0; rr < 6; ++rr)  a[rr] = Ls[kk][tyy + 32 * rr];
#pragma unroll
            for (int cc = 0; cc < 12; ++cc) bb[cc] = Ls[kk][tx + 16 * cc];
#pragma unroll
            for (int rr = 0; rr < 6; ++rr)
#pragma unroll
                for (int cc = 0; cc < 12; ++cc)
                    acc[rr][cc] = fmaf(a[rr], bb[cc], acc[rr][cc]);
        }
    }

    float* Gb = G + b * C_IN * C_IN;
#pragma unroll
    for (int rr = 0; rr < 6; ++rr)
#pragma unroll
        for (int cc = 0; cc < 12; ++cc)
            atomicAdd(&Gb[(tyy + 32 * rr) * C_IN + tx + 16 * cc], acc[rr][cc]);
}

// ---------------- generic 64x64-tile GEMM (fp32 out; fallback path) ----------------
__global__ __launch_bounds__(256) void gemm64_kernel(const float* __restrict__ A,
                                                     const float* __restrict__ B,
                                                     float* __restrict__ C,
                                                     int K, int N,
                                                     long aStride, long bStride, long cStride) {
    int mi0 = blockIdx.x * 64;
    int nj0 = blockIdx.y * 64;
    int b   = blockIdx.z;

    __shared__ float As[16][68];
    __shared__ float Bs[16][68];

    int tid = threadIdx.x;
    int tx = tid & 15, ty = tid >> 4;
    int lrow = tid >> 2, lk = (tid & 3) * 4;
    int ldk = tid >> 4, ldn = (tid & 15) * 4;

    const float* Ab = A + b * aStride;
    const float* Bb = B + b * bStride;

    float acc[4][4] = {};

    for (int k0 = 0; k0 < K; k0 += 16) {
        float4 av = *(const float4*)(Ab + (size_t)(mi0 + lrow) * K + k0 + lk);
        float4 bv = *(const float4*)(Bb + (size_t)(k0 + ldk) * N + nj0 + ldn);
        __syncthreads();
        As[lk + 0][lrow] = av.x; As[lk + 1][lrow] = av.y;
        As[lk + 2][lrow] = av.z; As[lk + 3][lrow] = av.w;
        *(float4*)&Bs[ldk][ldn] = bv;
        __syncthreads();
#pragma unroll
        for (int kk = 0; kk < 16; kk++) {
            float4 a = *(const float4*)&As[kk][ty * 4];
            float4 bb = *(const float4*)&Bs[kk][tx * 4];
            acc[0][0] += a.x * bb.x; acc[0][1] += a.x * bb.y; acc[0][2] += a.x * bb.z; acc[0][3] += a.x * bb.w;
            acc[1][0] += a.y * bb.x; acc[1][1] += a.y * bb.y; acc[1][2] += a.y * bb.z; acc[1][3] += a.y * bb.w;
            acc[2][0] += a.z * bb.x; acc[2][1] += a.z * bb.y; acc[2][2] += a.z * bb.z; acc[2][3] += a.z * bb.w;
            acc[3][0] += a.w * bb.x; acc[3][1] += a.w * bb.y; acc[3][2] += a.w * bb.z; acc[3][3] += a.w * bb.w;
        }
    }

    float* Cb = C + b * cStride;
#pragma unroll
    for (int r = 0; r < 4; r++) {
        float4 v = { acc[r][0], acc[r][1], acc[r][2], acc[r][3] };
        *(float4*)(Cb + (size_t)(mi0 + ty * 4 + r) * N + nj0 + tx * 4) = v;
    }
}

// ---------------- same GEMM, bf16 packed output (fallback path) ----------------
__global__ __launch_bounds__(256) void gemm64bf_kernel(const float* __restrict__ A,
                                                       const float* __restrict__ B,
                                                       unsigned short* __restrict__ C,
                                                       int K, int N,
                                                       long aStride, long bStride, long cStride) {
    int mi0 = blockIdx.x * 64;
    int nj0 = blockIdx.y * 64;
    int b   = blockIdx.z;

    __shared__ float As[16][68];
    __shared__ float Bs[16][68];

    int tid = threadIdx.x;
    int tx = tid & 15, ty = tid >> 4;
    int lrow = tid >> 2, lk = (tid & 3) * 4;
    int ldk = tid >> 4, ldn = (tid & 15) * 4;

    const float* Ab = A + b * aStride;
    const float* Bb = B + b * bStride;

    float acc[4][4] = {};

    for (int k0 = 0; k0 < K; k0 += 16) {
        float4 av = *(const float4*)(Ab + (size_t)(mi0 + lrow) * K + k0 + lk);
        float4 bv = *(const float4*)(Bb + (size_t)(k0 + ldk) * N + nj0 + ldn);
        __syncthreads();
        As[lk + 0][lrow] = av.x; As[lk + 1][lrow] = av.y;
        As[lk + 2][lrow] = av.z; As[lk + 3][lrow] = av.w;
        *(float4*)&Bs[ldk][ldn] = bv;
        __syncthreads();
#pragma unroll
        for (int kk = 0; kk < 16; kk++) {
            float4 a = *(const float4*)&As[kk][ty * 4];
            float4 bb = *(const float4*)&Bs[kk][tx * 4];
            acc[0][0] += a.x * bb.x; acc[0][1] += a.x * bb.y; acc[0][2] += a.x * bb.z; acc[0][3] += a.x * bb.w;
            acc[1][0] += a.y * bb.x; acc[1][1] += a.y * bb.y; acc[1][2] += a.y * bb.z; acc[1][3] += a.y * bb.w;
            acc[2][0] += a.z * bb.x; acc[2][1] += a.z * bb.y; acc[2][2] += a.z * bb.z; acc[2][3] += a.z * bb.w;
            acc[3][0] += a.w * bb.x; acc[3][1] += a.w * bb.y; acc[3][2] += a.w * bb.z; acc[3][3] += a.w * bb.w;
        }
    }

    unsigned short* Cb = C + b * cStride;
#pragma unroll
    for (int r = 0; r < 4; r++) {
        union { unsigned long long q; unsigned int u[2]; } pk;
        pk.u[0] = pk_bf16(acc[r][0], acc[r][1]);
        pk.u[1] = pk_bf16(acc[r][2], acc[r][3]);
        *(unsigned long long*)&Cb[(size_t)(mi0 + ty * 4 + r) * N + nj0 + tx * 4] = pk.q;
    }
}

// ---------------- fallback fused sim/softmax/M ----------------
__global__ __launch_bounds__(256) void simsoftm_kernel(const float* __restrict__ T,
                                                       const float* __restrict__ wk,
                                                       const float* __restrict__ wv,
                                                       float* __restrict__ M) {
    int b = blockIdx.x, h = blockIdx.y;

    __shared__ float As[16][68];
    __shared__ float Bs[16][68];
    __shared__ float At[64][68];

    int tid = threadIdx.x;
    int tx = tid & 15, ty = tid >> 4;
    int ldk = tid >> 4, ldn = (tid & 15) * 4;
    int lrow = tid >> 2, lk = (tid & 3) * 4;

    const float* Th  = T + (size_t)b * 512 * C_IN + (size_t)(h * 64) * C_IN;
    const float* wkh = wk + (size_t)(h * 64) * C_IN;
    const float* wvh = wv + (size_t)(h * 64) * C_IN;

    float acc[4][4] = {};
    for (int k0 = 0; k0 < C_IN; k0 += 16) {
        float4 av = *(const float4*)(Th  + (size_t)lrow * C_IN + k0 + lk);
        float4 bv = *(const float4*)(wkh + (size_t)lrow * C_IN + k0 + lk);
        __syncthreads();
        As[lk + 0][lrow] = av.x; As[lk + 1][lrow] = av.y;
        As[lk + 2][lrow] = av.z; As[lk + 3][lrow] = av.w;
        Bs[lk + 0][lrow] = bv.x; Bs[lk + 1][lrow] = bv.y;
        Bs[lk + 2][lrow] = bv.z; Bs[lk + 3][lrow] = bv.w;
        __syncthreads();
#pragma unroll
        for (int kk = 0; kk < 16; kk++) {
            float4 a = *(const float4*)&As[kk][ty * 4];
            float4 bb = *(const float4*)&Bs[kk][tx * 4];
            acc[0][0] += a.x * bb.x; acc[0][1] += a.x * bb.y; acc[0][2] += a.x * bb.z; acc[0][3] += a.x * bb.w;
            acc[1][0] += a.y * bb.x; acc[1][1] += a.y * bb.y; acc[1][2] += a.y * bb.z; acc[1][3] += a.y * bb.w;
            acc[2][0] += a.z * bb.x; acc[2][1] += a.z * bb.y; acc[2][2] += a.z * bb.z; acc[2][3] += a.z * bb.w;
            acc[3][0] += a.w * bb.x; acc[3][1] += a.w * bb.y; acc[3][2] += a.w * bb.z; acc[3][3] += a.w * bb.w;
        }
    }

#pragma unroll
    for (int r = 0; r < 4; r++) {
        float s0 = acc[r][0] * ATT_SCALE, s1 = acc[r][1] * ATT_SCALE;
        float s2 = acc[r][2] * ATT_SCALE, s3 = acc[r][3] * ATT_SCALE;
        float mx = fmaxf(fmaxf(s0, s1), fmaxf(s2, s3));
        mx = fmaxf(mx, __shfl_xor(mx, 1));
        mx = fmaxf(mx, __shfl_xor(mx, 2));
        mx = fmaxf(mx, __shfl_xor(mx, 4));
        mx = fmaxf(mx, __shfl_xor(mx, 8));
        float e0 = __expf(s0 - mx), e1 = __expf(s1 - mx);
        float e2 = __expf(s2 - mx), e3 = __expf(s3 - mx);
        float sum = (e0 + e1) + (e2 + e3);
        sum += __shfl_xor(sum, 1);
        sum += __shfl_xor(sum, 2);
        sum += __shfl_xor(sum, 4);
        sum += __shfl_xor(sum, 8);
        float inv = 1.0f / sum;
        At[tx * 4 + 0][ty * 4 + r] = e0 * inv;
        At[tx * 4 + 1][ty * 4 + r] = e1 * inv;
        At[tx * 4 + 2][ty * 4 + r] = e2 * inv;
        At[tx * 4 + 3][ty * 4 + r] = e3 * inv;
    }

    float* Mb = M + (size_t)b * 512 * C_IN + (size_t)(h * 64) * C_IN;
    for (int nj = 0; nj < C_IN; nj += 64) {
        float acc2[4][4] = {};
        for (int j0 = 0; j0 < 64; j0 += 16) {
            float4 bv = *(const float4*)(wvh + (size_t)(j0 + ldk) * C_IN + nj + ldn);
            __syncthreads();
            *(float4*)&Bs[ldk][ldn] = bv;
            __syncthreads();
#pragma unroll
            for (int kk = 0; kk < 16; kk++) {
                float4 a = *(const float4*)&At[j0 + kk][ty * 4];
                float4 bb = *(const float4*)&Bs[kk][tx * 4];
                acc2[0][0] += a.x * bb.x; acc2[0][1] += a.x * bb.y; acc2[0][2] += a.x * bb.z; acc2[0][3] += a.x * bb.w;
                acc2[1][0] += a.y * bb.x; acc2[1][1] += a.y * bb.y; acc2[1][2] += a.y * bb.z; acc2[1][3] += a.y * bb.w;
                acc2[2][0] += a.z * bb.x; acc2[2][1] += a.z * bb.y; acc2[2][2] += a.z * bb.z; acc2[2][3] += a.z * bb.w;
                acc2[3][0] += a.w * bb.x; acc2[3][1] += a.w * bb.y; acc2[3][2] += a.w * bb.z; acc2[3][3] += a.w * bb.w;
            }
        }
#pragma unroll
        for (int r = 0; r < 4; r++) {
            float4 v = { acc2[r][0], acc2[r][1], acc2[r][2], acc2[r][3] };
            *(float4*)(Mb + (size_t)(ty * 4 + r) * C_IN + nj + tx * 4) = v;
        }
    }
}

// ---------------- out = W*x + bo, bf16 MFMA. grid (256, NB), block 256 (4 waves) ----------------
__global__ __launch_bounds__(256) void final_kernel(const float* __restrict__ x,
                                                    const unsigned short* __restrict__ Wbf,
                                                    const float* __restrict__ bo,
                                                    float* __restrict__ out) {
    int n0 = blockIdx.x * 128;
    int b  = blockIdx.y;

    __shared__ unsigned short Xs[128 * 40];

    int tid  = threadIdx.x;
    int wave = tid >> 6;
    int lane = tid & 63;
    int wm   = (wave & 1) * 96;
    int wn   = (wave >> 1) * 64;
    int lm   = lane & 15, quad = lane >> 4;

    int sn  = tid & 127;
    int skh = (tid >> 7) * 16;

    const float* xsrc = x + (size_t)b * C_IN * S_TOT + n0 + sn;
    const unsigned short* Wb = Wbf + b * C_IN * C_IN;

    f32x4 acc[6][4];
#pragma unroll
    for (int mt = 0; mt < 6; mt++)
#pragma unroll
        for (int nt = 0; nt < 4; nt++) acc[mt][nt] = (f32x4){0.f, 0.f, 0.f, 0.f};

    float pf[16];
#pragma unroll
    for (int j = 0; j < 16; j++) pf[j] = xsrc[(size_t)(skh + j) * S_TOT];

    for (int kc = 0; kc < 6; ++kc) {
        int k0 = kc * 32;
        __syncthreads();
        {
            union { uint4 q; unsigned int u[4]; } pk0, pk1;
#pragma unroll
            for (int j = 0; j < 4; j++) {
                pk0.u[j] = pk_bf16(pf[2 * j],     pf[2 * j + 1]);
                pk1.u[j] = pk_bf16(pf[8 + 2 * j], pf[8 + 2 * j + 1]);
            }
            *(uint4*)&Xs[sn * 40 + skh + 0] = pk0.q;
            *(uint4*)&Xs[sn * 40 + skh + 8] = pk1.q;
        }
        __syncthreads();
        if (kc + 1 < 6) {
            int kn = k0 + 32;
#pragma unroll
            for (int j = 0; j < 16; j++) pf[j] = xsrc[(size_t)(kn + skh + j) * S_TOT];
        }

        short8 afr[6];
#pragma unroll
        for (int mt = 0; mt < 6; mt++)
            afr[mt] = *(const short8*)(Wb + (size_t)(wm + mt * 16 + lm) * C_IN + k0 + quad * 8);
#pragma unroll
        for (int nt = 0; nt < 4; nt++) {
            short8 bfr = *(const short8*)&Xs[(wn + nt * 16 + lm) * 40 + quad * 8];
#pragma unroll
            for (int mt = 0; mt < 6; mt++)
                acc[mt][nt] = __builtin_amdgcn_mfma_f32_16x16x32_bf16(afr[mt], bfr, acc[mt][nt], 0, 0, 0);
        }
    }

#pragma unroll
    for (int mt = 0; mt < 6; mt++) {
#pragma unroll
        for (int r = 0; r < 4; r++) {
            int m = wm + mt * 16 + quad * 4 + r;
            float bias = bo[m];
            float* op = out + ((size_t)b * C_IN + m) * S_TOT + n0;
#pragma unroll
            for (int nt = 0; nt < 4; nt++)
                op[wn + nt * 16 + lm] = acc[mt][nt][r] + bias;
        }
    }
}

extern "C" void kernel_launch(void* const* d_in, const int* in_sizes, int n_in,
                              void* d_out, int out_size, void* d_ws, size_t ws_size,
                              hipStream_t stream) {
    const float* x  = (const float*)d_in[0];
    const float* wq = (const float*)d_in[1];
    const float* wk = (const float*)d_in[2];
    const float* wv = (const float*)d_in[3];
    const float* wo = (const float*)d_in[4];
    const float* bo = (const float*)d_in[5];
    float* out = (float*)d_out;
    float* ws  = (float*)d_ws;

    unsigned short* gWbf = (unsigned short*)(ws + WBF_OFF);

    bool bigws = ws_size >= (size_t)WS_END * sizeof(float);
    if (bigws) {
        // 3 dispatches: gram(+weight split, zeroes barriers) -> middle (36 blk, 2 barriers) -> final
        gram_partial<<<dim3(NSLICE, NB), 512, 0, stream>>>(x, wq, wk, wv, wo, ws);
        mega_mid<<<dim3(MEGA_NBLK), 256, 0, stream>>>(ws);
        final_kernel<<<dim3(256, NB), 256, 0, stream>>>(x, gWbf, bo, out);
    } else {
        // fallback: original proven chain
        float* gG = ws + G_OFF;
        float* gT = ws + T_OFF;
        float* gM = ws + M_OFF;
        hipMemsetAsync(gG, 0, G_SZ * sizeof(float), stream);
        gram_atomic<<<dim3(NSLICE, NB), 512, 0, stream>>>(x, gG);
        gemm64_kernel<<<dim3(8, 3, NB), 256, 0, stream>>>(
            wq, gG, gT, C_IN, C_IN, 0L, (long)(C_IN * C_IN), (long)(512 * C_IN));
        simsoftm_kernel<<<dim3(NB, NH), 256, 0, stream>>>(gT, wk, wv, gM);
        gemm64bf_kernel<<<dim3(3, 3, NB), 256, 0, stream>>>(
            wo, gM, gWbf, 512, C_IN, 0L, (long)(512 * C_IN), (long)(C_IN * C_IN));
        final_kernel<<<dim3(256, NB), 256, 0, stream>>>(x, gWbf, bo, out);
    }
}

// Round 9
// 206.396 us; speedup vs baseline: 1.6801x; 1.0708x over previous
//
#include <hip/hip_runtime.h>
#include <hip/hip_bf16.h>

#define S_TOT 32768
#define C_IN 192
#define NB 2
#define NH 8
#define DH 64
#define ATT_SCALE 0.125f
#define NSLICE 128
#define GR_CH 8
#define GR_BK 32

// ---------------- workspace layout (float units) ----------------
#define G_OFF   0
#define G_SZ    (NB * C_IN * C_IN)      // main path: Gf fp32 accumulator
#define T_OFF   (G_OFF + G_SZ)
#define T_SZ    (NB * 512 * C_IN)       // main path: WF fp32 accumulator (first 73728)
#define M_OFF   (T_OFF + T_SZ)
#define M_SZ    (NB * 512 * C_IN)
#define WBF_OFF (M_OFF + M_SZ)
#define WBF_SZ  (NB * C_IN * C_IN / 2)
#define P_OFF   (WBF_OFF + WBF_SZ)
#define P_SZ    (NB * NSLICE * C_IN * C_IN)

// split-weight / split-G / split-Z storage (each array = N ushorts = N/2 floats)
#define WEL      (512 * C_IN)
#define SPL_FL   (WEL / 2)
#define WQH_OFF  (P_OFF + P_SZ)
#define WQM_OFF  (WQH_OFF + SPL_FL)
#define WQL_OFF  (WQM_OFF + SPL_FL)
#define WKH_OFF  (WQL_OFF + SPL_FL)
#define WKM_OFF  (WKH_OFF + SPL_FL)
#define WKL_OFF  (WKM_OFF + SPL_FL)
#define WOH_OFF  (WKL_OFF + SPL_FL)
#define WOL_OFF  (WOH_OFF + SPL_FL)
#define WVTH_OFF (WOL_OFF + SPL_FL)
#define WVTL_OFF (WVTH_OFF + SPL_FL)
#define GEL      (C_IN * C_IN)
#define GH_OFF   (WVTL_OFF + SPL_FL)
#define GM_OFF   (GH_OFF + NB * GEL / 2)
#define GL_OFF   (GM_OFF + NB * GEL / 2)
#define ZEL      (C_IN * 512)
#define ZH_OFF   (GL_OFF + NB * GEL / 2)
#define ZL_OFF   (ZH_OFF + NB * ZEL / 2)
#define WS_END   (ZL_OFF + NB * ZEL / 2)

#define GF_OFF   G_OFF     // fp32 G accumulator (NB*GEL floats)
#define WF_OFF   T_OFF     // fp32 W accumulator (NB*GEL floats)

typedef __attribute__((ext_vector_type(8))) short short8;
typedef __attribute__((ext_vector_type(4))) float f32x4;

__device__ inline unsigned short f2bf(float f) {   // RNE
    unsigned int u = __float_as_uint(f);
    u += 0x7fffu + ((u >> 16) & 1u);
    return (unsigned short)(u >> 16);
}

__device__ inline unsigned int pk_bf16(float a, float b) {  // packed RNE pair
    __hip_bfloat162 t = __float22bfloat162_rn(make_float2(a, b));
    unsigned int bits;
    __builtin_memcpy(&bits, &t, 4);
    return bits;
}

__device__ inline void split_bf(float v, unsigned short& h, unsigned short& l) {
    unsigned int u = __float_as_uint(v);
    h = (unsigned short)(u >> 16);
    float hf = __uint_as_float(u & 0xffff0000u);
    l = f2bf(v - hf);
}

__device__ inline void split3_bf(float v, unsigned short& h, unsigned short& m, unsigned short& l) {
    unsigned int u = __float_as_uint(v);
    h = (unsigned short)(u >> 16);
    float hf = __uint_as_float(u & 0xffff0000u);
    float r1 = v - hf;
    unsigned int u1 = __float_as_uint(r1);
    m = (unsigned short)(u1 >> 16);
    float mf = __uint_as_float(u1 & 0xffff0000u);
    l = f2bf(r1 - mf);
}

__device__ inline unsigned long long pack4(const unsigned short* s) {
    return (unsigned long long)s[0] | ((unsigned long long)s[1] << 16)
         | ((unsigned long long)s[2] << 32) | ((unsigned long long)s[3] << 48);
}

// One unit of weight pre-splitting; 98304 units over gram_partial's 256 blocks x 384 lanes.
__device__ inline void split_unit(int u, const float* wq, const float* wk,
                                  const float* wv, const float* wo, float* ws) {
    int region = u / 24576;
    int r = u - region * 24576;
    if (region < 3) {
        const float* src = (region == 0) ? wq : (region == 1) ? wk : wo;
        int i = r * 4;
        float4 v = *(const float4*)(src + i);
        if (region < 2) {
            unsigned short h[4], m[4], l[4];
            split3_bf(v.x, h[0], m[0], l[0]);
            split3_bf(v.y, h[1], m[1], l[1]);
            split3_bf(v.z, h[2], m[2], l[2]);
            split3_bf(v.w, h[3], m[3], l[3]);
            int base = (region == 0) ? WQH_OFF : WKH_OFF;
            *(unsigned long long*)((unsigned short*)(ws + base) + i)              = pack4(h);
            *(unsigned long long*)((unsigned short*)(ws + base + SPL_FL) + i)     = pack4(m);
            *(unsigned long long*)((unsigned short*)(ws + base + 2 * SPL_FL) + i) = pack4(l);
        } else {
            unsigned short h[4], l[4];
            split_bf(v.x, h[0], l[0]);
            split_bf(v.y, h[1], l[1]);
            split_bf(v.z, h[2], l[2]);
            split_bf(v.w, h[3], l[3]);
            *(unsigned long long*)((unsigned short*)(ws + WOH_OFF) + i) = pack4(h);
            *(unsigned long long*)((unsigned short*)(ws + WOL_OFF) + i) = pack4(l);
        }
    } else {
        int j4 = r / 192;
        int c  = r - j4 * 192;
        int j  = j4 * 4;
        unsigned short h[4], l[4];
#pragma unroll
        for (int jj = 0; jj < 4; ++jj)
            split_bf(wv[(size_t)(j + jj) * C_IN + c], h[jj], l[jj]);
        *(unsigned long long*)((unsigned short*)(ws + WVTH_OFF) + c * 512 + j) = pack4(h);
        *(unsigned long long*)((unsigned short*)(ws + WVTL_OFF) + c * 512 + j) = pack4(l);
    }
}

// ---------------- Gram via split-bf16 MFMA: P[b][slice] = X-slice * X-slice^T ----------------
__global__ __launch_bounds__(512, 2) void gram_partial(const float* __restrict__ x,
                                                       const float* __restrict__ wq,
                                                       const float* __restrict__ wk,
                                                       const float* __restrict__ wv,
                                                       const float* __restrict__ wo,
                                                       float* __restrict__ ws) {
    int b     = blockIdx.y;
    int slice = blockIdx.x;
    int kbase = slice * (GR_CH * GR_BK);

    __shared__ unsigned short Hs[192 * 40];
    __shared__ unsigned short Lo[192 * 40];

    int tid  = threadIdx.x;
    int wave = tid >> 6;
    int lane = tid & 63;
    int rw   = wave & 3;
    int cw   = wave >> 2;
    int lm   = lane & 15, quad = lane >> 4;

    // zero the fp32 G and W accumulators for this iteration (atomics target)
    if (blockIdx.x == 0 && blockIdx.y == 0) {
#pragma unroll
        for (int u = 0; u < 72; ++u) {
            int i4 = (u * 512 + tid) * 4;
            if (i4 < 2 * NB * GEL) {
                float* dst = (i4 < NB * GEL) ? (ws + GF_OFF + i4)
                                             : (ws + WF_OFF + (i4 - NB * GEL));
                *(float4*)dst = (float4){0.f, 0.f, 0.f, 0.f};
            }
        }
    }

    const float* xb = x + (size_t)b * C_IN * S_TOT;

    int lc[3], lkq[3];
#pragma unroll
    for (int q = 0; q < 3; q++) { int id = tid + 512 * q; lc[q] = id >> 3; lkq[q] = id & 7; }

    f32x4 acc[3][6];
#pragma unroll
    for (int mt = 0; mt < 3; mt++)
#pragma unroll
        for (int nt = 0; nt < 6; nt++) acc[mt][nt] = (f32x4){0.f, 0.f, 0.f, 0.f};

    float4 pf[3];
#pragma unroll
    for (int q = 0; q < 3; q++)
        pf[q] = *(const float4*)(xb + (size_t)lc[q] * S_TOT + kbase + lkq[q] * 4);

    if (tid < 384) split_unit((b * NSLICE + slice) * 384 + tid, wq, wk, wv, wo, ws);

    for (int ch = 0; ch < GR_CH; ++ch) {
        __syncthreads();
#pragma unroll
        for (int q = 0; q < 3; q++) {
            unsigned short h[4], l[4];
            split_bf(pf[q].x, h[0], l[0]);
            split_bf(pf[q].y, h[1], l[1]);
            split_bf(pf[q].z, h[2], l[2]);
            split_bf(pf[q].w, h[3], l[3]);
            *(unsigned long long*)&Hs[lc[q] * 40 + lkq[q] * 4] = pack4(h);
            *(unsigned long long*)&Lo[lc[q] * 40 + lkq[q] * 4] = pack4(l);
        }
        __syncthreads();
        if (ch + 1 < GR_CH) {
            int k0 = kbase + (ch + 1) * GR_BK;
#pragma unroll
            for (int q = 0; q < 3; q++)
                pf[q] = *(const float4*)(xb + (size_t)lc[q] * S_TOT + k0 + lkq[q] * 4);
        }

        short8 ah[3], al[3];
#pragma unroll
        for (int mt = 0; mt < 3; mt++) {
            int row = 48 * rw + mt * 16 + lm;
            ah[mt] = *(const short8*)&Hs[row * 40 + quad * 8];
            al[mt] = *(const short8*)&Lo[row * 40 + quad * 8];
        }
#pragma unroll
        for (int nt = 0; nt < 6; nt++) {
            int col = 96 * cw + nt * 16 + lm;
            short8 bh = *(const short8*)&Hs[col * 40 + quad * 8];
            short8 bl = *(const short8*)&Lo[col * 40 + quad * 8];
#pragma unroll
            for (int mt = 0; mt < 3; mt++) {
                acc[mt][nt] = __builtin_amdgcn_mfma_f32_16x16x32_bf16(ah[mt], bh, acc[mt][nt], 0, 0, 0);
                acc[mt][nt] = __builtin_amdgcn_mfma_f32_16x16x32_bf16(ah[mt], bl, acc[mt][nt], 0, 0, 0);
                acc[mt][nt] = __builtin_amdgcn_mfma_f32_16x16x32_bf16(al[mt], bh, acc[mt][nt], 0, 0, 0);
            }
        }
    }

    float* Pb = ws + P_OFF + ((size_t)(b * NSLICE + slice)) * (C_IN * C_IN);
#pragma unroll
    for (int mt = 0; mt < 3; mt++) {
#pragma unroll
        for (int r = 0; r < 4; r++) {
            int row = 48 * rw + mt * 16 + quad * 4 + r;
#pragma unroll
            for (int nt = 0; nt < 6; nt++)
                Pb[row * C_IN + 96 * cw + nt * 16 + lm] = acc[mt][nt][r];
        }
    }
}

// ---------------- greduce: P (37.75MB) -> fp32 Gf via atomics. grid (36,8,NB)=576 blk ----------------
__global__ __launch_bounds__(256) void greduce(float* __restrict__ ws) {
    int cb = blockIdx.x, sg = blockIdx.y, b = blockIdx.z;
    int idx4 = (cb * 256 + threadIdx.x) * 4;
    const float* Pb = ws + P_OFF + (size_t)(b * NSLICE + sg * 16) * GEL + idx4;
    float4 v[16];
#pragma unroll
    for (int s = 0; s < 16; ++s)
        v[s] = *(const float4*)(Pb + (size_t)s * GEL);
    float4 acc = {0.f, 0.f, 0.f, 0.f};
#pragma unroll
    for (int s = 0; s < 16; ++s) {
        acc.x += v[s].x; acc.y += v[s].y; acc.z += v[s].z; acc.w += v[s].w;
    }
    float* g = ws + GF_OFF + (size_t)b * GEL + idx4;
    atomicAdd(g + 0, acc.x);
    atomicAdd(g + 1, acc.y);
    atomicAdd(g + 2, acc.z);
    atomicAdd(g + 3, acc.w);
}

// ---------------- gsplit: Gf fp32 -> triple-split GH/GM/GL. grid (36,NB)=72 blk ----------------
__global__ __launch_bounds__(256) void gsplit(float* __restrict__ ws) {
    int b = blockIdx.y;
    int idx4 = (blockIdx.x * 256 + threadIdx.x) * 4;
    float4 s = *(const float4*)(ws + GF_OFF + (size_t)b * GEL + idx4);
    unsigned short h[4], m[4], l[4];
    split3_bf(s.x, h[0], m[0], l[0]);
    split3_bf(s.y, h[1], m[1], l[1]);
    split3_bf(s.z, h[2], m[2], l[2]);
    split3_bf(s.w, h[3], m[3], l[3]);
    *(unsigned long long*)((unsigned short*)(ws + GH_OFF) + (size_t)b * GEL + idx4) = pack4(h);
    *(unsigned long long*)((unsigned short*)(ws + GM_OFF) + (size_t)b * GEL + idx4) = pack4(m);
    *(unsigned long long*)((unsigned short*)(ws + GL_OFF) + (size_t)b * GEL + idx4) = pack4(l);
}

// ---------------- bc: Qt=Wq_h*G -> LDS -> sim -> softmax -> Z. grid (NB,NH)=16 blk ----------------
__global__ __launch_bounds__(256) void bc_kernel(float* __restrict__ ws) {
    int b = blockIdx.x, h = blockIdx.y;
    int tid  = threadIdx.x;
    int wave = tid >> 6;
    int lane = tid & 63;
    int lm   = lane & 15, quad = lane >> 4;

    __shared__ float SQ[64 * 196];   // Qt fp32 [64][196]; later reused as attn^T [64][68]

    const unsigned short* AH = (const unsigned short*)(ws + WQH_OFF);
    const unsigned short* AM = (const unsigned short*)(ws + WQM_OFF);
    const unsigned short* AL = (const unsigned short*)(ws + WQL_OFF);
    const unsigned short* GH = (const unsigned short*)(ws + GH_OFF) + (size_t)b * GEL;
    const unsigned short* GM = (const unsigned short*)(ws + GM_OFF) + (size_t)b * GEL;
    const unsigned short* GL = (const unsigned short*)(ws + GL_OFF) + (size_t)b * GEL;
    const unsigned short* KH = (const unsigned short*)(ws + WKH_OFF);
    const unsigned short* KM = (const unsigned short*)(ws + WKM_OFF);
    const unsigned short* KL = (const unsigned short*)(ws + WKL_OFF);
    const unsigned short* WOHp = (const unsigned short*)(ws + WOH_OFF);
    const unsigned short* WOLp = (const unsigned short*)(ws + WOL_OFF);

    // ---- B: Qt = Wq_h * G (64x192), 6-term triple MFMA, fp32 into LDS ----
    f32x4 qacc[12];
#pragma unroll
    for (int ct = 0; ct < 12; ++ct) qacc[ct] = (f32x4){0.f, 0.f, 0.f, 0.f};

    int qr = (h * 64 + wave * 16 + lm) * C_IN;
#pragma unroll
    for (int hf = 0; hf < 2; ++hf) {
#pragma unroll
        for (int ch = 0; ch < 6; ++ch) {
            int k0 = ch * 32 + quad * 8;
            short8 aH = *(const short8*)(AH + qr + k0);
            short8 aM = *(const short8*)(AM + qr + k0);
            short8 aL = *(const short8*)(AL + qr + k0);
            short8 bH[6], bM[6], bL[6];
#pragma unroll
            for (int ct = 0; ct < 6; ++ct) {
                int gr = ((hf * 6 + ct) * 16 + lm) * C_IN + k0;
                bH[ct] = *(const short8*)(GH + gr);
                bM[ct] = *(const short8*)(GM + gr);
                bL[ct] = *(const short8*)(GL + gr);
            }
#pragma unroll
            for (int ct = 0; ct < 6; ++ct) {
                int q = hf * 6 + ct;
                qacc[q] = __builtin_amdgcn_mfma_f32_16x16x32_bf16(aH, bH[ct], qacc[q], 0, 0, 0);
                qacc[q] = __builtin_amdgcn_mfma_f32_16x16x32_bf16(aH, bM[ct], qacc[q], 0, 0, 0);
                qacc[q] = __builtin_amdgcn_mfma_f32_16x16x32_bf16(aM, bH[ct], qacc[q], 0, 0, 0);
                qacc[q] = __builtin_amdgcn_mfma_f32_16x16x32_bf16(aH, bL[ct], qacc[q], 0, 0, 0);
                qacc[q] = __builtin_amdgcn_mfma_f32_16x16x32_bf16(aM, bM[ct], qacc[q], 0, 0, 0);
                qacc[q] = __builtin_amdgcn_mfma_f32_16x16x32_bf16(aL, bH[ct], qacc[q], 0, 0, 0);
            }
        }
    }
#pragma unroll
    for (int ct = 0; ct < 12; ++ct)
#pragma unroll
        for (int r = 0; r < 4; ++r)
            SQ[(wave * 16 + quad * 4 + r) * 196 + ct * 16 + lm] = qacc[ct][r];
    __syncthreads();

    // ---- C1: sim = Qt * Wk_h^T (64x64), Qt triple-split on read ----
    f32x4 sacc[4];
#pragma unroll
    for (int ct = 0; ct < 4; ++ct) sacc[ct] = (f32x4){0.f, 0.f, 0.f, 0.f};
#pragma unroll
    for (int ch = 0; ch < 6; ++ch) {
        int k0 = ch * 32 + quad * 8;
        float qv[8];
        *(float4*)&qv[0] = *(const float4*)&SQ[(wave * 16 + lm) * 196 + k0];
        *(float4*)&qv[4] = *(const float4*)&SQ[(wave * 16 + lm) * 196 + k0 + 4];
        short8 aH, aM, aL;
#pragma unroll
        for (int j = 0; j < 8; ++j) {
            unsigned short hh, mm, ll;
            split3_bf(qv[j], hh, mm, ll);
            aH[j] = (short)hh; aM[j] = (short)mm; aL[j] = (short)ll;
        }
        short8 bH[4], bM[4], bL[4];
#pragma unroll
        for (int ct = 0; ct < 4; ++ct) {
            int kr = (h * 64 + ct * 16 + lm) * C_IN + k0;
            bH[ct] = *(const short8*)(KH + kr);
            bM[ct] = *(const short8*)(KM + kr);
            bL[ct] = *(const short8*)(KL + kr);
        }
#pragma unroll
        for (int ct = 0; ct < 4; ++ct) {
            sacc[ct] = __builtin_amdgcn_mfma_f32_16x16x32_bf16(aH, bH[ct], sacc[ct], 0, 0, 0);
            sacc[ct] = __builtin_amdgcn_mfma_f32_16x16x32_bf16(aH, bM[ct], sacc[ct], 0, 0, 0);
            sacc[ct] = __builtin_amdgcn_mfma_f32_16x16x32_bf16(aM, bH[ct], sacc[ct], 0, 0, 0);
            sacc[ct] = __builtin_amdgcn_mfma_f32_16x16x32_bf16(aH, bL[ct], sacc[ct], 0, 0, 0);
            sacc[ct] = __builtin_amdgcn_mfma_f32_16x16x32_bf16(aM, bM[ct], sacc[ct], 0, 0, 0);
            sacc[ct] = __builtin_amdgcn_mfma_f32_16x16x32_bf16(aL, bH[ct], sacc[ct], 0, 0, 0);
        }
    }
    __syncthreads();   // all Qt reads done before attn^T overwrites SQ

    // ---- softmax over j (cols), store attn^T into At[j][i] ----
    float* At = SQ;    // [64][68]
#pragma unroll
    for (int r = 0; r < 4; ++r) {
        float s0 = sacc[0][r] * ATT_SCALE;
        float s1 = sacc[1][r] * ATT_SCALE;
        float s2 = sacc[2][r] * ATT_SCALE;
        float s3 = sacc[3][r] * ATT_SCALE;
        float mx = fmaxf(fmaxf(s0, s1), fmaxf(s2, s3));
        mx = fmaxf(mx, __shfl_xor(mx, 1));
        mx = fmaxf(mx, __shfl_xor(mx, 2));
        mx = fmaxf(mx, __shfl_xor(mx, 4));
        mx = fmaxf(mx, __shfl_xor(mx, 8));
        float e0 = __expf(s0 - mx), e1 = __expf(s1 - mx);
        float e2 = __expf(s2 - mx), e3 = __expf(s3 - mx);
        float sum = (e0 + e1) + (e2 + e3);
        sum += __shfl_xor(sum, 1);
        sum += __shfl_xor(sum, 2);
        sum += __shfl_xor(sum, 4);
        sum += __shfl_xor(sum, 8);
        float inv = 1.0f / sum;
        int i = wave * 16 + quad * 4 + r;
        At[lm * 68 + i]        = e0 * inv;
        At[(16 + lm) * 68 + i] = e1 * inv;
        At[(32 + lm) * 68 + i] = e2 * inv;
        At[(48 + lm) * 68 + i] = e3 * inv;
    }
    __syncthreads();

    // ---- C2: Z_h = Wo[:, 64h:64h+64] * attn (192x64), double-split ----
    f32x4 zacc[3][4];
#pragma unroll
    for (int mt = 0; mt < 3; ++mt)
#pragma unroll
        for (int ct = 0; ct < 4; ++ct) zacc[mt][ct] = (f32x4){0.f, 0.f, 0.f, 0.f};

#pragma unroll
    for (int ch = 0; ch < 2; ++ch) {
        int k0 = ch * 32 + quad * 8;
        short8 bH[4], bL[4];
#pragma unroll
        for (int ct = 0; ct < 4; ++ct) {
            float av[8];
            *(float4*)&av[0] = *(const float4*)&At[(ct * 16 + lm) * 68 + k0];
            *(float4*)&av[4] = *(const float4*)&At[(ct * 16 + lm) * 68 + k0 + 4];
#pragma unroll
            for (int j = 0; j < 8; ++j) {
                unsigned short hh, ll;
                split_bf(av[j], hh, ll);
                bH[ct][j] = (short)hh; bL[ct][j] = (short)ll;
            }
        }
#pragma unroll
        for (int mt = 0; mt < 3; ++mt) {
            int orow = (wave * 48 + mt * 16 + lm) * 512 + h * 64 + k0;
            short8 aH = *(const short8*)(WOHp + orow);
            short8 aL = *(const short8*)(WOLp + orow);
#pragma unroll
            for (int ct = 0; ct < 4; ++ct) {
                zacc[mt][ct] = __builtin_amdgcn_mfma_f32_16x16x32_bf16(aH, bH[ct], zacc[mt][ct], 0, 0, 0);
                zacc[mt][ct] = __builtin_amdgcn_mfma_f32_16x16x32_bf16(aH, bL[ct], zacc[mt][ct], 0, 0, 0);
                zacc[mt][ct] = __builtin_amdgcn_mfma_f32_16x16x32_bf16(aL, bH[ct], zacc[mt][ct], 0, 0, 0);
            }
        }
    }

    unsigned short* ZHb = (unsigned short*)(ws + ZH_OFF) + (size_t)b * ZEL;
    unsigned short* ZLb = (unsigned short*)(ws + ZL_OFF) + (size_t)b * ZEL;
#pragma unroll
    for (int mt = 0; mt < 3; ++mt)
#pragma unroll
        for (int r = 0; r < 4; ++r) {
            int o = wave * 48 + mt * 16 + quad * 4 + r;
#pragma unroll
            for (int ct = 0; ct < 4; ++ct) {
                unsigned short hh, ll;
                split_bf(zacc[mt][ct][r], hh, ll);
                int idx = o * 512 + h * 64 + ct * 16 + lm;
                ZHb[idx] = hh;
                ZLb[idx] = ll;
            }
        }
}

// ---------------- wmix_f: W += Z*Wv^T per kseg, fp32 atomics. grid (NB,4,8)=64 blk ----------------
__global__ __launch_bounds__(256) void wmix_f(float* __restrict__ ws) {
    int b = blockIdx.x;
    int half = blockIdx.y >> 1, cwD = blockIdx.y & 1;
    int kseg = blockIdx.z;
    int tid  = threadIdx.x;
    int wave = tid >> 6, lane = tid & 63;
    int lm = lane & 15, quad = lane >> 4;
    int rw = wave;

    const unsigned short* ZHb = (const unsigned short*)(ws + ZH_OFF) + (size_t)b * ZEL;
    const unsigned short* ZLb = (const unsigned short*)(ws + ZL_OFF) + (size_t)b * ZEL;
    const unsigned short* VTH = (const unsigned short*)(ws + WVTH_OFF);
    const unsigned short* VTL = (const unsigned short*)(ws + WVTL_OFF);

    f32x4 acc[3][3];
#pragma unroll
    for (int mt = 0; mt < 3; ++mt)
#pragma unroll
        for (int ct = 0; ct < 3; ++ct) acc[mt][ct] = (f32x4){0.f, 0.f, 0.f, 0.f};

#pragma unroll
    for (int ch = 0; ch < 2; ++ch) {
        int k0 = kseg * 64 + ch * 32 + quad * 8;
        short8 aH[3], aL[3];
#pragma unroll
        for (int mt = 0; mt < 3; ++mt) {
            int o = (rw * 48 + mt * 16 + lm) * 512 + k0;
            aH[mt] = *(const short8*)(ZHb + o);
            aL[mt] = *(const short8*)(ZLb + o);
        }
        short8 bH[3], bL[3];
#pragma unroll
        for (int ct = 0; ct < 3; ++ct) {
            int c = (half * 96 + cwD * 48 + ct * 16 + lm) * 512 + k0;
            bH[ct] = *(const short8*)(VTH + c);
            bL[ct] = *(const short8*)(VTL + c);
        }
#pragma unroll
        for (int ct = 0; ct < 3; ++ct)
#pragma unroll
            for (int mt = 0; mt < 3; ++mt) {
                acc[mt][ct] = __builtin_amdgcn_mfma_f32_16x16x32_bf16(aH[mt], bH[ct], acc[mt][ct], 0, 0, 0);
                acc[mt][ct] = __builtin_amdgcn_mfma_f32_16x16x32_bf16(aH[mt], bL[ct], acc[mt][ct], 0, 0, 0);
                acc[mt][ct] = __builtin_amdgcn_mfma_f32_16x16x32_bf16(aL[mt], bH[ct], acc[mt][ct], 0, 0, 0);
            }
    }

    float* Wb = ws + WF_OFF + (size_t)b * GEL;
#pragma unroll
    for (int mt = 0; mt < 3; ++mt)
#pragma unroll
        for (int r = 0; r < 4; ++r) {
            int m = rw * 48 + mt * 16 + quad * 4 + r;
#pragma unroll
            for (int ct = 0; ct < 3; ++ct)
                atomicAdd(&Wb[m * C_IN + half * 96 + cwD * 48 + ct * 16 + lm], acc[mt][ct][r]);
        }
}

// ---------------- final: out = W*x + bo, W fp32 -> bf16 inline. grid (256,NB) ----------------
__global__ __launch_bounds__(256) void final_f(const float* __restrict__ x,
                                               const float* __restrict__ ws_wf,
                                               const float* __restrict__ bo,
                                               float* __restrict__ out) {
    int n0 = blockIdx.x * 128;
    int b  = blockIdx.y;

    __shared__ unsigned short Xs[128 * 40];

    int tid  = threadIdx.x;
    int wave = tid >> 6;
    int lane = tid & 63;
    int wm   = (wave & 1) * 96;
    int wn   = (wave >> 1) * 64;
    int lm   = lane & 15, quad = lane >> 4;

    int sn  = tid & 127;
    int skh = (tid >> 7) * 16;

    const float* xsrc = x + (size_t)b * C_IN * S_TOT + n0 + sn;
    const float* Wb = ws_wf + (size_t)b * GEL;

    f32x4 acc[6][4];
#pragma unroll
    for (int mt = 0; mt < 6; mt++)
#pragma unroll
        for (int nt = 0; nt < 4; nt++) acc[mt][nt] = (f32x4){0.f, 0.f, 0.f, 0.f};

    float pf[16];
#pragma unroll
    for (int j = 0; j < 16; j++) pf[j] = xsrc[(size_t)(skh + j) * S_TOT];

    for (int kc = 0; kc < 6; ++kc) {
        int k0 = kc * 32;
        __syncthreads();
        {
            union { uint4 q; unsigned int u[4]; } pk0, pk1;
#pragma unroll
            for (int j = 0; j < 4; j++) {
                pk0.u[j] = pk_bf16(pf[2 * j],     pf[2 * j + 1]);
                pk1.u[j] = pk_bf16(pf[8 + 2 * j], pf[8 + 2 * j + 1]);
            }
            *(uint4*)&Xs[sn * 40 + skh + 0] = pk0.q;
            *(uint4*)&Xs[sn * 40 + skh + 8] = pk1.q;
        }
        __syncthreads();
        if (kc + 1 < 6) {
            int kn = k0 + 32;
#pragma unroll
            for (int j = 0; j < 16; j++) pf[j] = xsrc[(size_t)(kn + skh + j) * S_TOT];
        }

        short8 afr[6];
#pragma unroll
        for (int mt = 0; mt < 6; mt++) {
            const float* wr = Wb + (size_t)(wm + mt * 16 + lm) * C_IN + k0 + quad * 8;
            float4 w0 = *(const float4*)(wr);
            float4 w1 = *(const float4*)(wr + 4);
            short8 a;
            a[0] = (short)f2bf(w0.x); a[1] = (short)f2bf(w0.y);
            a[2] = (short)f2bf(w0.z); a[3] = (short)f2bf(w0.w);
            a[4] = (short)f2bf(w1.x); a[5] = (short)f2bf(w1.y);
            a[6] = (short)f2bf(w1.z); a[7] = (short)f2bf(w1.w);
            afr[mt] = a;
        }
#pragma unroll
        for (int nt = 0; nt < 4; nt++) {
            short8 bfr = *(const short8*)&Xs[(wn + nt * 16 + lm) * 40 + quad * 8];
#pragma unroll
            for (int mt = 0; mt < 6; mt++)
                acc[mt][nt] = __builtin_amdgcn_mfma_f32_16x16x32_bf16(afr[mt], bfr, acc[mt][nt], 0, 0, 0);
        }
    }

#pragma unroll
    for (int mt = 0; mt < 6; mt++) {
#pragma unroll
        for (int r = 0; r < 4; r++) {
            int m = wm + mt * 16 + quad * 4 + r;
            float bias = bo[m];
            float* op = out + ((size_t)b * C_IN + m) * S_TOT + n0;
#pragma unroll
            for (int nt = 0; nt < 4; nt++)
                op[wn + nt * 16 + lm] = acc[mt][nt][r] + bias;
        }
    }
}

// ---------------- Gram fallback (fp32 atomic; used only if ws too small) ----------------
__global__ __launch_bounds__(512, 2) void gram_atomic(const float* __restrict__ x,
                                                      float* __restrict__ G) {
    int b     = blockIdx.y;
    int kbase = blockIdx.x * (GR_CH * GR_BK);

    __shared__ float Ls[GR_BK][196];

    int tid = threadIdx.x;
    int tx  = tid & 15;
    int tyy = tid >> 4;

    const float* xb = x + (size_t)b * C_IN * S_TOT;

    int lc[3], lkq[3];
#pragma unroll
    for (int q = 0; q < 3; q++) { int id = tid + 512 * q; lc[q] = id >> 3; lkq[q] = id & 7; }

    float acc[6][12] = {};
    float4 pf[3];

#pragma unroll
    for (int q = 0; q < 3; q++)
        pf[q] = *(const float4*)(xb + (size_t)lc[q] * S_TOT + kbase + lkq[q] * 4);

    for (int ch = 0; ch < GR_CH; ++ch) {
        __syncthreads();
#pragma unroll
        for (int q = 0; q < 3; q++) {
            Ls[lkq[q] * 4 + 0][lc[q]] = pf[q].x;
            Ls[lkq[q] * 4 + 1][lc[q]] = pf[q].y;
            Ls[lkq[q] * 4 + 2][lc[q]] = pf[q].z;
            Ls[lkq[q] * 4 + 3][lc[q]] = pf[q].w;
        }
        __syncthreads();
        if (ch + 1 < GR_CH) {
            int k0 = kbase + (ch + 1) * GR_BK;
#pragma unroll
            for (int q = 0; q < 3; q++)
                pf[q] = *(const float4*)(xb + (size_t)lc[q] * S_TOT + k0 + lkq[q] * 4);
        }
#pragma unroll
        for (int kk = 0; kk < GR_BK; ++kk) {
            float a[6], bb[12];
#pragma unroll
            for (int rr = 0; rr < 6; ++rr)  a[rr] = Ls[kk][tyy + 32 * rr];
#pragma unroll
            for (int cc = 0; cc < 12; ++cc) bb[cc] = Ls[kk][tx + 16 * cc];
#pragma unroll
            for (int rr = 0; rr < 6; ++rr)
#pragma unroll
                for (int cc = 0; cc < 12; ++cc)
                    acc[rr][cc] = fmaf(a[rr], bb[cc], acc[rr][cc]);
        }
    }

    float* Gb = G + b * C_IN * C_IN;
#pragma unroll
    for (int rr = 0; rr < 6; ++rr)
#pragma unroll
        for (int cc = 0; cc < 12; ++cc)
            atomicAdd(&Gb[(tyy + 32 * rr) * C_IN + tx + 16 * cc], acc[rr][cc]);
}

// ---------------- generic 64x64-tile GEMM (fp32 out; fallback path) ----------------
__global__ __launch_bounds__(256) void gemm64_kernel(const float* __restrict__ A,
                                                     const float* __restrict__ B,
                                                     float* __restrict__ C,
                                                     int K, int N,
                                                     long aStride, long bStride, long cStride) {
    int mi0 = blockIdx.x * 64;
    int nj0 = blockIdx.y * 64;
    int b   = blockIdx.z;

    __shared__ float As[16][68];
    __shared__ float Bs[16][68];

    int tid = threadIdx.x;
    int tx = tid & 15, ty = tid >> 4;
    int lrow = tid >> 2, lk = (tid & 3) * 4;
    int ldk = tid >> 4, ldn = (tid & 15) * 4;

    const float* Ab = A + b * aStride;
    const float* Bb = B + b * bStride;

    float acc[4][4] = {};

    for (int k0 = 0; k0 < K; k0 += 16) {
        float4 av = *(const float4*)(Ab + (size_t)(mi0 + lrow) * K + k0 + lk);
        float4 bv = *(const float4*)(Bb + (size_t)(k0 + ldk) * N + nj0 + ldn);
        __syncthreads();
        As[lk + 0][lrow] = av.x; As[lk + 1][lrow] = av.y;
        As[lk + 2][lrow] = av.z; As[lk + 3][lrow] = av.w;
        *(float4*)&Bs[ldk][ldn] = bv;
        __syncthreads();
#pragma unroll
        for (int kk = 0; kk < 16; kk++) {
            float4 a = *(const float4*)&As[kk][ty * 4];
            float4 bb = *(const float4*)&Bs[kk][tx * 4];
            acc[0][0] += a.x * bb.x; acc[0][1] += a.x * bb.y; acc[0][2] += a.x * bb.z; acc[0][3] += a.x * bb.w;
            acc[1][0] += a.y * bb.x; acc[1][1] += a.y * bb.y; acc[1][2] += a.y * bb.z; acc[1][3] += a.y * bb.w;
            acc[2][0] += a.z * bb.x; acc[2][1] += a.z * bb.y; acc[2][2] += a.z * bb.z; acc[2][3] += a.z * bb.w;
            acc[3][0] += a.w * bb.x; acc[3][1] += a.w * bb.y; acc[3][2] += a.w * bb.z; acc[3][3] += a.w * bb.w;
        }
    }

    float* Cb = C + b * cStride;
#pragma unroll
    for (int r = 0; r < 4; r++) {
        float4 v = { acc[r][0], acc[r][1], acc[r][2], acc[r][3] };
        *(float4*)(Cb + (size_t)(mi0 + ty * 4 + r) * N + nj0 + tx * 4) = v;
    }
}

// ---------------- same GEMM, bf16 packed output (fallback path) ----------------
__global__ __launch_bounds__(256) void gemm64bf_kernel(const float* __restrict__ A,
                                                       const float* __restrict__ B,
                                                       unsigned short* __restrict__ C,
                                                       int K, int N,
                                                       long aStride, long bStride, long cStride) {
    int mi0 = blockIdx.x * 64;
    int nj0 = blockIdx.y * 64;
    int b   = blockIdx.z;

    __shared__ float As[16][68];
    __shared__ float Bs[16][68];

    int tid = threadIdx.x;
    int tx = tid & 15, ty = tid >> 4;
    int lrow = tid >> 2, lk = (tid & 3) * 4;
    int ldk = tid >> 4, ldn = (tid & 15) * 4;

    const float* Ab = A + b * aStride;
    const float* Bb = B + b * bStride;

    float acc[4][4] = {};

    for (int k0 = 0; k0 < K; k0 += 16) {
        float4 av = *(const float4*)(Ab + (size_t)(mi0 + lrow) * K + k0 + lk);
        float4 bv = *(const float4*)(Bb + (size_t)(k0 + ldk) * N + nj0 + ldn);
        __syncthreads();
        As[lk + 0][lrow] = av.x; As[lk + 1][lrow] = av.y;
        As[lk + 2][lrow] = av.z; As[lk + 3][lrow] = av.w;
        *(float4*)&Bs[ldk][ldn] = bv;
        __syncthreads();
#pragma unroll
        for (int kk = 0; kk < 16; kk++) {
            float4 a = *(const float4*)&As[kk][ty * 4];
            float4 bb = *(const float4*)&Bs[kk][tx * 4];
            acc[0][0] += a.x * bb.x; acc[0][1] += a.x * bb.y; acc[0][2] += a.x * bb.z; acc[0][3] += a.x * bb.w;
            acc[1][0] += a.y * bb.x; acc[1][1] += a.y * bb.y; acc[1][2] += a.y * bb.z; acc[1][3] += a.y * bb.w;
            acc[2][0] += a.z * bb.x; acc[2][1] += a.z * bb.y; acc[2][2] += a.z * bb.z; acc[2][3] += a.z * bb.w;
            acc[3][0] += a.w * bb.x; acc[3][1] += a.w * bb.y; acc[3][2] += a.w * bb.z; acc[3][3] += a.w * bb.w;
        }
    }

    unsigned short* Cb = C + b * cStride;
#pragma unroll
    for (int r = 0; r < 4; r++) {
        union { unsigned long long q; unsigned int u[2]; } pk;
        pk.u[0] = pk_bf16(acc[r][0], acc[r][1]);
        pk.u[1] = pk_bf16(acc[r][2], acc[r][3]);
        *(unsigned long long*)&Cb[(size_t)(mi0 + ty * 4 + r) * N + nj0 + tx * 4] = pk.q;
    }
}

// ---------------- fallback fused sim/softmax/M ----------------
__global__ __launch_bounds__(256) void simsoftm_kernel(const float* __restrict__ T,
                                                       const float* __restrict__ wk,
                                                       const float* __restrict__ wv,
                                                       float* __restrict__ M) {
    int b = blockIdx.x, h = blockIdx.y;

    __shared__ float As[16][68];
    __shared__ float Bs[16][68];
    __shared__ float At[64][68];

    int tid = threadIdx.x;
    int tx = tid & 15, ty = tid >> 4;
    int ldk = tid >> 4, ldn = (tid & 15) * 4;
    int lrow = tid >> 2, lk = (tid & 3) * 4;

    const float* Th  = T + (size_t)b * 512 * C_IN + (size_t)(h * 64) * C_IN;
    const float* wkh = wk + (size_t)(h * 64) * C_IN;
    const float* wvh = wv + (size_t)(h * 64) * C_IN;

    float acc[4][4] = {};
    for (int k0 = 0; k0 < C_IN; k0 += 16) {
        float4 av = *(const float4*)(Th  + (size_t)lrow * C_IN + k0 + lk);
        float4 bv = *(const float4*)(wkh + (size_t)lrow * C_IN + k0 + lk);
        __syncthreads();
        As[lk + 0][lrow] = av.x; As[lk + 1][lrow] = av.y;
        As[lk + 2][lrow] = av.z; As[lk + 3][lrow] = av.w;
        Bs[lk + 0][lrow] = bv.x; Bs[lk + 1][lrow] = bv.y;
        Bs[lk + 2][lrow] = bv.z; Bs[lk + 3][lrow] = bv.w;
        __syncthreads();
#pragma unroll
        for (int kk = 0; kk < 16; kk++) {
            float4 a = *(const float4*)&As[kk][ty * 4];
            float4 bb = *(const float4*)&Bs[kk][tx * 4];
            acc[0][0] += a.x * bb.x; acc[0][1] += a.x * bb.y; acc[0][2] += a.x * bb.z; acc[0][3] += a.x * bb.w;
            acc[1][0] += a.y * bb.x; acc[1][1] += a.y * bb.y; acc[1][2] += a.y * bb.z; acc[1][3] += a.y * bb.w;
            acc[2][0] += a.z * bb.x; acc[2][1] += a.z * bb.y; acc[2][2] += a.z * bb.z; acc[2][3] += a.z * bb.w;
            acc[3][0] += a.w * bb.x; acc[3][1] += a.w * bb.y; acc[3][2] += a.w * bb.z; acc[3][3] += a.w * bb.w;
        }
    }

#pragma unroll
    for (int r = 0; r < 4; r++) {
        float s0 = acc[r][0] * ATT_SCALE, s1 = acc[r][1] * ATT_SCALE;
        float s2 = acc[r][2] * ATT_SCALE, s3 = acc[r][3] * ATT_SCALE;
        float mx = fmaxf(fmaxf(s0, s1), fmaxf(s2, s3));
        mx = fmaxf(mx, __shfl_xor(mx, 1));
        mx = fmaxf(mx, __shfl_xor(mx, 2));
        mx = fmaxf(mx, __shfl_xor(mx, 4));
        mx = fmaxf(mx, __shfl_xor(mx, 8));
        float e0 = __expf(s0 - mx), e1 = __expf(s1 - mx);
        float e2 = __expf(s2 - mx), e3 = __expf(s3 - mx);
        float sum = (e0 + e1) + (e2 + e3);
        sum += __shfl_xor(sum, 1);
        sum += __shfl_xor(sum, 2);
        sum += __shfl_xor(sum, 4);
        sum += __shfl_xor(sum, 8);
        float inv = 1.0f / sum;
        At[tx * 4 + 0][ty * 4 + r] = e0 * inv;
        At[tx * 4 + 1][ty * 4 + r] = e1 * inv;
        At[tx * 4 + 2][ty * 4 + r] = e2 * inv;
        At[tx * 4 + 3][ty * 4 + r] = e3 * inv;
    }

    float* Mb = M + (size_t)b * 512 * C_IN + (size_t)(h * 64) * C_IN;
    for (int nj = 0; nj < C_IN; nj += 64) {
        float acc2[4][4] = {};
        for (int j0 = 0; j0 < 64; j0 += 16) {
            float4 bv = *(const float4*)(wvh + (size_t)(j0 + ldk) * C_IN + nj + ldn);
            __syncthreads();
            *(float4*)&Bs[ldk][ldn] = bv;
            __syncthreads();
#pragma unroll
            for (int kk = 0; kk < 16; kk++) {
                float4 a = *(const float4*)&At[j0 + kk][ty * 4];
                float4 bb = *(const float4*)&Bs[kk][tx * 4];
                acc2[0][0] += a.x * bb.x; acc2[0][1] += a.x * bb.y; acc2[0][2] += a.x * bb.z; acc2[0][3] += a.x * bb.w;
                acc2[1][0] += a.y * bb.x; acc2[1][1] += a.y * bb.y; acc2[1][2] += a.y * bb.z; acc2[1][3] += a.y * bb.w;
                acc2[2][0] += a.z * bb.x; acc2[2][1] += a.z * bb.y; acc2[2][2] += a.z * bb.z; acc2[2][3] += a.z * bb.w;
                acc2[3][0] += a.w * bb.x; acc2[3][1] += a.w * bb.y; acc2[3][2] += a.w * bb.z; acc2[3][3] += a.w * bb.w;
            }
        }
#pragma unroll
        for (int r = 0; r < 4; r++) {
            float4 v = { acc2[r][0], acc2[r][1], acc2[r][2], acc2[r][3] };
            *(float4*)(Mb + (size_t)(ty * 4 + r) * C_IN + nj + tx * 4) = v;
        }
    }
}

// ---------------- fallback final (bf16 W) ----------------
__global__ __launch_bounds__(256) void final_kernel(const float* __restrict__ x,
                                                    const unsigned short* __restrict__ Wbf,
                                                    const float* __restrict__ bo,
                                                    float* __restrict__ out) {
    int n0 = blockIdx.x * 128;
    int b  = blockIdx.y;

    __shared__ unsigned short Xs[128 * 40];

    int tid  = threadIdx.x;
    int wave = tid >> 6;
    int lane = tid & 63;
    int wm   = (wave & 1) * 96;
    int wn   = (wave >> 1) * 64;
    int lm   = lane & 15, quad = lane >> 4;

    int sn  = tid & 127;
    int skh = (tid >> 7) * 16;

    const float* xsrc = x + (size_t)b * C_IN * S_TOT + n0 + sn;
    const unsigned short* Wb = Wbf + b * C_IN * C_IN;

    f32x4 acc[6][4];
#pragma unroll
    for (int mt = 0; mt < 6; mt++)
#pragma unroll
        for (int nt = 0; nt < 4; nt++) acc[mt][nt] = (f32x4){0.f, 0.f, 0.f, 0.f};

    float pf[16];
#pragma unroll
    for (int j = 0; j < 16; j++) pf[j] = xsrc[(size_t)(skh + j) * S_TOT];

    for (int kc = 0; kc < 6; ++kc) {
        int k0 = kc * 32;
        __syncthreads();
        {
            union { uint4 q; unsigned int u[4]; } pk0, pk1;
#pragma unroll
            for (int j = 0; j < 4; j++) {
                pk0.u[j] = pk_bf16(pf[2 * j],     pf[2 * j + 1]);
                pk1.u[j] = pk_bf16(pf[8 + 2 * j], pf[8 + 2 * j + 1]);
            }
            *(uint4*)&Xs[sn * 40 + skh + 0] = pk0.q;
            *(uint4*)&Xs[sn * 40 + skh + 8] = pk1.q;
        }
        __syncthreads();
        if (kc + 1 < 6) {
            int kn = k0 + 32;
#pragma unroll
            for (int j = 0; j < 16; j++) pf[j] = xsrc[(size_t)(kn + skh + j) * S_TOT];
        }

        short8 afr[6];
#pragma unroll
        for (int mt = 0; mt < 6; mt++)
            afr[mt] = *(const short8*)(Wb + (size_t)(wm + mt * 16 + lm) * C_IN + k0 + quad * 8);
#pragma unroll
        for (int nt = 0; nt < 4; nt++) {
            short8 bfr = *(const short8*)&Xs[(wn + nt * 16 + lm) * 40 + quad * 8];
#pragma unroll
            for (int mt = 0; mt < 6; mt++)
                acc[mt][nt] = __builtin_amdgcn_mfma_f32_16x16x32_bf16(afr[mt], bfr, acc[mt][nt], 0, 0, 0);
        }
    }

#pragma unroll
    for (int mt = 0; mt < 6; mt++) {
#pragma unroll
        for (int r = 0; r < 4; r++) {
            int m = wm + mt * 16 + quad * 4 + r;
            float bias = bo[m];
            float* op = out + ((size_t)b * C_IN + m) * S_TOT + n0;
#pragma unroll
            for (int nt = 0; nt < 4; nt++)
                op[wn + nt * 16 + lm] = acc[mt][nt][r] + bias;
        }
    }
}

extern "C" void kernel_launch(void* const* d_in, const int* in_sizes, int n_in,
                              void* d_out, int out_size, void* d_ws, size_t ws_size,
                              hipStream_t stream) {
    const float* x  = (const float*)d_in[0];
    const float* wq = (const float*)d_in[1];
    const float* wk = (const float*)d_in[2];
    const float* wv = (const float*)d_in[3];
    const float* wo = (const float*)d_in[4];
    const float* bo = (const float*)d_in[5];
    float* out = (float*)d_out;
    float* ws  = (float*)d_ws;

    bool bigws = ws_size >= (size_t)WS_END * sizeof(float);
    if (bigws) {
        // 7 dispatches, no barriers, every grid sized for its bandwidth:
        gram_partial<<<dim3(NSLICE, NB), 512, 0, stream>>>(x, wq, wk, wv, wo, ws);
        greduce<<<dim3(36, 8, NB), 256, 0, stream>>>(ws);
        gsplit<<<dim3(36, NB), 256, 0, stream>>>(ws);
        bc_kernel<<<dim3(NB, NH), 256, 0, stream>>>(ws);
        wmix_f<<<dim3(NB, 4, 8), 256, 0, stream>>>(ws);
        final_f<<<dim3(256, NB), 256, 0, stream>>>(x, ws + WF_OFF, bo, out);
    } else {
        // fallback: original proven chain
        float* gG = ws + G_OFF;
        float* gT = ws + T_OFF;
        float* gM = ws + M_OFF;
        unsigned short* gWbf = (unsigned short*)(ws + WBF_OFF);
        hipMemsetAsync(gG, 0, G_SZ * sizeof(float), stream);
        gram_atomic<<<dim3(NSLICE, NB), 512, 0, stream>>>(x, gG);
        gemm64_kernel<<<dim3(8, 3, NB), 256, 0, stream>>>(
            wq, gG, gT, C_IN, C_IN, 0L, (long)(C_IN * C_IN), (long)(512 * C_IN));
        simsoftm_kernel<<<dim3(NB, NH), 256, 0, stream>>>(gT, wk, wv, gM);
        gemm64bf_kernel<<<dim3(3, 3, NB), 256, 0, stream>>>(
            wo, gM, gWbf, 512, C_IN, 0L, (long)(512 * C_IN), (long)(C_IN * C_IN));
        final_kernel<<<dim3(256, NB), 256, 0, stream>>>(x, gWbf, bo, out);
    }
}

// Round 10
// 192.894 us; speedup vs baseline: 1.7977x; 1.0700x over previous
//
#include <hip/hip_runtime.h>
#include <hip/hip_bf16.h>

#define S_TOT 32768
#define C_IN 192
#define NB 2
#define NH 8
#define DH 64
#define ATT_SCALE 0.125f
#define NSLICE 128
#define GR_CH 8
#define GR_BK 32

// ---------------- workspace layout (float units) ----------------
#define G_OFF   0
#define G_SZ    (NB * C_IN * C_IN)      // main path: Gf fp32 accumulator
#define T_OFF   (G_OFF + G_SZ)
#define T_SZ    (NB * 512 * C_IN)       // main path: WF fp32 accumulator (first 73728)
#define M_OFF   (T_OFF + T_SZ)
#define M_SZ    (NB * 512 * C_IN)
#define WBF_OFF (M_OFF + M_SZ)
#define WBF_SZ  (NB * C_IN * C_IN / 2)
#define P_OFF   (WBF_OFF + WBF_SZ)
#define P_SZ    (NB * NSLICE * C_IN * C_IN)

// split-weight storage (each array = N ushorts = N/2 floats)
#define WEL      (512 * C_IN)
#define SPL_FL   (WEL / 2)
#define WQH_OFF  (P_OFF + P_SZ)
#define WQM_OFF  (WQH_OFF + SPL_FL)
#define WQL_OFF  (WQM_OFF + SPL_FL)
#define WKH_OFF  (WQL_OFF + SPL_FL)
#define WKM_OFF  (WKH_OFF + SPL_FL)
#define WKL_OFF  (WKM_OFF + SPL_FL)
#define WOH_OFF  (WKL_OFF + SPL_FL)
#define WOL_OFF  (WOH_OFF + SPL_FL)
#define WVTH_OFF (WOL_OFF + SPL_FL)
#define WVTL_OFF (WVTH_OFF + SPL_FL)
#define GEL      (C_IN * C_IN)
#define GH_OFF   (WVTL_OFF + SPL_FL)
#define GM_OFF   (GH_OFF + NB * GEL / 2)
#define GL_OFF   (GM_OFF + NB * GEL / 2)
#define ZEL      (C_IN * 512)
#define ZH_OFF   (GL_OFF + NB * GEL / 2)
#define ZL_OFF   (ZH_OFF + NB * ZEL / 2)
#define WS_END   (ZL_OFF + NB * ZEL / 2)

#define GF_OFF   G_OFF     // fp32 G accumulator (NB*GEL floats)
#define WF_OFF   T_OFF     // fp32 W accumulator (NB*GEL floats)
// Qt fp32 aliased into the (dead after greduce) P region
#define PT_EL    (512 * C_IN)
#define QTF_OFF  P_OFF

typedef __attribute__((ext_vector_type(8))) short short8;
typedef __attribute__((ext_vector_type(4))) float f32x4;

__device__ inline unsigned short f2bf(float f) {   // RNE
    unsigned int u = __float_as_uint(f);
    u += 0x7fffu + ((u >> 16) & 1u);
    return (unsigned short)(u >> 16);
}

__device__ inline unsigned int pk_bf16(float a, float b) {  // packed RNE pair
    __hip_bfloat162 t = __float22bfloat162_rn(make_float2(a, b));
    unsigned int bits;
    __builtin_memcpy(&bits, &t, 4);
    return bits;
}

__device__ inline void split_bf(float v, unsigned short& h, unsigned short& l) {
    unsigned int u = __float_as_uint(v);
    h = (unsigned short)(u >> 16);
    float hf = __uint_as_float(u & 0xffff0000u);
    l = f2bf(v - hf);
}

__device__ inline void split3_bf(float v, unsigned short& h, unsigned short& m, unsigned short& l) {
    unsigned int u = __float_as_uint(v);
    h = (unsigned short)(u >> 16);
    float hf = __uint_as_float(u & 0xffff0000u);
    float r1 = v - hf;
    unsigned int u1 = __float_as_uint(r1);
    m = (unsigned short)(u1 >> 16);
    float mf = __uint_as_float(u1 & 0xffff0000u);
    l = f2bf(r1 - mf);
}

__device__ inline unsigned long long pack4(const unsigned short* s) {
    return (unsigned long long)s[0] | ((unsigned long long)s[1] << 16)
         | ((unsigned long long)s[2] << 32) | ((unsigned long long)s[3] << 48);
}

// One unit of weight pre-splitting; 98304 units over gram_partial's 256 blocks x 384 lanes.
__device__ inline void split_unit(int u, const float* wq, const float* wk,
                                  const float* wv, const float* wo, float* ws) {
    int region = u / 24576;
    int r = u - region * 24576;
    if (region < 3) {
        const float* src = (region == 0) ? wq : (region == 1) ? wk : wo;
        int i = r * 4;
        float4 v = *(const float4*)(src + i);
        if (region < 2) {
            unsigned short h[4], m[4], l[4];
            split3_bf(v.x, h[0], m[0], l[0]);
            split3_bf(v.y, h[1], m[1], l[1]);
            split3_bf(v.z, h[2], m[2], l[2]);
            split3_bf(v.w, h[3], m[3], l[3]);
            int base = (region == 0) ? WQH_OFF : WKH_OFF;
            *(unsigned long long*)((unsigned short*)(ws + base) + i)              = pack4(h);
            *(unsigned long long*)((unsigned short*)(ws + base + SPL_FL) + i)     = pack4(m);
            *(unsigned long long*)((unsigned short*)(ws + base + 2 * SPL_FL) + i) = pack4(l);
        } else {
            unsigned short h[4], l[4];
            split_bf(v.x, h[0], l[0]);
            split_bf(v.y, h[1], l[1]);
            split_bf(v.z, h[2], l[2]);
            split_bf(v.w, h[3], l[3]);
            *(unsigned long long*)((unsigned short*)(ws + WOH_OFF) + i) = pack4(h);
            *(unsigned long long*)((unsigned short*)(ws + WOL_OFF) + i) = pack4(l);
        }
    } else {
        int j4 = r / 192;
        int c  = r - j4 * 192;
        int j  = j4 * 4;
        unsigned short h[4], l[4];
#pragma unroll
        for (int jj = 0; jj < 4; ++jj)
            split_bf(wv[(size_t)(j + jj) * C_IN + c], h[jj], l[jj]);
        *(unsigned long long*)((unsigned short*)(ws + WVTH_OFF) + c * 512 + j) = pack4(h);
        *(unsigned long long*)((unsigned short*)(ws + WVTL_OFF) + c * 512 + j) = pack4(l);
    }
}

// ---------------- Gram via split-bf16 MFMA: P[b][slice] = X-slice * X-slice^T ----------------
__global__ __launch_bounds__(512, 2) void gram_partial(const float* __restrict__ x,
                                                       const float* __restrict__ wq,
                                                       const float* __restrict__ wk,
                                                       const float* __restrict__ wv,
                                                       const float* __restrict__ wo,
                                                       float* __restrict__ ws) {
    int b     = blockIdx.y;
    int slice = blockIdx.x;
    int kbase = slice * (GR_CH * GR_BK);

    __shared__ unsigned short Hs[192 * 40];
    __shared__ unsigned short Lo[192 * 40];

    int tid  = threadIdx.x;
    int wave = tid >> 6;
    int lane = tid & 63;
    int rw   = wave & 3;
    int cw   = wave >> 2;
    int lm   = lane & 15, quad = lane >> 4;

    // zero the fp32 G and W accumulators for this iteration (atomics target)
    if (blockIdx.x == 0 && blockIdx.y == 0) {
#pragma unroll
        for (int u = 0; u < 72; ++u) {
            int i4 = (u * 512 + tid) * 4;
            if (i4 < 2 * NB * GEL) {
                float* dst = (i4 < NB * GEL) ? (ws + GF_OFF + i4)
                                             : (ws + WF_OFF + (i4 - NB * GEL));
                *(float4*)dst = (float4){0.f, 0.f, 0.f, 0.f};
            }
        }
    }

    const float* xb = x + (size_t)b * C_IN * S_TOT;

    int lc[3], lkq[3];
#pragma unroll
    for (int q = 0; q < 3; q++) { int id = tid + 512 * q; lc[q] = id >> 3; lkq[q] = id & 7; }

    f32x4 acc[3][6];
#pragma unroll
    for (int mt = 0; mt < 3; mt++)
#pragma unroll
        for (int nt = 0; nt < 6; nt++) acc[mt][nt] = (f32x4){0.f, 0.f, 0.f, 0.f};

    float4 pf[3];
#pragma unroll
    for (int q = 0; q < 3; q++)
        pf[q] = *(const float4*)(xb + (size_t)lc[q] * S_TOT + kbase + lkq[q] * 4);

    if (tid < 384) split_unit((b * NSLICE + slice) * 384 + tid, wq, wk, wv, wo, ws);

    for (int ch = 0; ch < GR_CH; ++ch) {
        __syncthreads();
#pragma unroll
        for (int q = 0; q < 3; q++) {
            unsigned short h[4], l[4];
            split_bf(pf[q].x, h[0], l[0]);
            split_bf(pf[q].y, h[1], l[1]);
            split_bf(pf[q].z, h[2], l[2]);
            split_bf(pf[q].w, h[3], l[3]);
            *(unsigned long long*)&Hs[lc[q] * 40 + lkq[q] * 4] = pack4(h);
            *(unsigned long long*)&Lo[lc[q] * 40 + lkq[q] * 4] = pack4(l);
        }
        __syncthreads();
        if (ch + 1 < GR_CH) {
            int k0 = kbase + (ch + 1) * GR_BK;
#pragma unroll
            for (int q = 0; q < 3; q++)
                pf[q] = *(const float4*)(xb + (size_t)lc[q] * S_TOT + k0 + lkq[q] * 4);
        }

        short8 ah[3], al[3];
#pragma unroll
        for (int mt = 0; mt < 3; mt++) {
            int row = 48 * rw + mt * 16 + lm;
            ah[mt] = *(const short8*)&Hs[row * 40 + quad * 8];
            al[mt] = *(const short8*)&Lo[row * 40 + quad * 8];
        }
#pragma unroll
        for (int nt = 0; nt < 6; nt++) {
            int col = 96 * cw + nt * 16 + lm;
            short8 bh = *(const short8*)&Hs[col * 40 + quad * 8];
            short8 bl = *(const short8*)&Lo[col * 40 + quad * 8];
#pragma unroll
            for (int mt = 0; mt < 3; mt++) {
                acc[mt][nt] = __builtin_amdgcn_mfma_f32_16x16x32_bf16(ah[mt], bh, acc[mt][nt], 0, 0, 0);
                acc[mt][nt] = __builtin_amdgcn_mfma_f32_16x16x32_bf16(ah[mt], bl, acc[mt][nt], 0, 0, 0);
                acc[mt][nt] = __builtin_amdgcn_mfma_f32_16x16x32_bf16(al[mt], bh, acc[mt][nt], 0, 0, 0);
            }
        }
    }

    float* Pb = ws + P_OFF + ((size_t)(b * NSLICE + slice)) * (C_IN * C_IN);
#pragma unroll
    for (int mt = 0; mt < 3; mt++) {
#pragma unroll
        for (int r = 0; r < 4; r++) {
            int row = 48 * rw + mt * 16 + quad * 4 + r;
#pragma unroll
            for (int nt = 0; nt < 6; nt++)
                Pb[row * C_IN + 96 * cw + nt * 16 + lm] = acc[mt][nt][r];
        }
    }
}

// ---------------- greduce: P (37.75MB) -> fp32 Gf via atomics. grid (36,8,NB)=576 blk ----------------
__global__ __launch_bounds__(256) void greduce(float* __restrict__ ws) {
    int cb = blockIdx.x, sg = blockIdx.y, b = blockIdx.z;
    int idx4 = (cb * 256 + threadIdx.x) * 4;
    const float* Pb = ws + P_OFF + (size_t)(b * NSLICE + sg * 16) * GEL + idx4;
    float4 v[16];
#pragma unroll
    for (int s = 0; s < 16; ++s)
        v[s] = *(const float4*)(Pb + (size_t)s * GEL);
    float4 acc = {0.f, 0.f, 0.f, 0.f};
#pragma unroll
    for (int s = 0; s < 16; ++s) {
        acc.x += v[s].x; acc.y += v[s].y; acc.z += v[s].z; acc.w += v[s].w;
    }
    float* g = ws + GF_OFF + (size_t)b * GEL + idx4;
    atomicAdd(g + 0, acc.x);
    atomicAdd(g + 1, acc.y);
    atomicAdd(g + 2, acc.z);
    atomicAdd(g + 3, acc.w);
}

// ---------------- proj: Qt = Wq*G, G split3 on the fly from Gf. grid (NB,NH,2)=32 blk ----------------
// Writes Qt fp32 into the (dead after greduce) P region.
__global__ __launch_bounds__(256) void proj_kernel(float* __restrict__ ws) {
    int b  = blockIdx.x;
    int h  = blockIdx.y;
    int cg = blockIdx.z;
    int tid = threadIdx.x, wave = tid >> 6, lane = tid & 63;
    int lm = lane & 15, quad = lane >> 4;

    const unsigned short* AH = (const unsigned short*)(ws + WQH_OFF);
    const unsigned short* AM = (const unsigned short*)(ws + WQM_OFF);
    const unsigned short* AL = (const unsigned short*)(ws + WQL_OFF);
    const float* Gf = ws + GF_OFF + (size_t)b * GEL;

    int arow = (h * 64 + wave * 16 + lm) * C_IN;

    f32x4 acc[6];
#pragma unroll
    for (int ct = 0; ct < 6; ++ct) acc[ct] = (f32x4){0.f, 0.f, 0.f, 0.f};

#pragma unroll
    for (int ch = 0; ch < 6; ++ch) {
        int k0 = ch * 32 + quad * 8;
        short8 aH = *(const short8*)(AH + arow + k0);
        short8 aM = *(const short8*)(AM + arow + k0);
        short8 aL = *(const short8*)(AL + arow + k0);
        float4 g0[6], g1[6];
#pragma unroll
        for (int ct = 0; ct < 6; ++ct) {
            int gr = (cg * 96 + ct * 16 + lm) * C_IN + k0;
            g0[ct] = *(const float4*)(Gf + gr);
            g1[ct] = *(const float4*)(Gf + gr + 4);
        }
        short8 bH[6], bM[6], bL[6];
#pragma unroll
        for (int ct = 0; ct < 6; ++ct) {
            float gv[8];
            *(float4*)&gv[0] = g0[ct];
            *(float4*)&gv[4] = g1[ct];
#pragma unroll
            for (int j = 0; j < 8; ++j) {
                unsigned short hh, mm, ll;
                split3_bf(gv[j], hh, mm, ll);
                bH[ct][j] = (short)hh; bM[ct][j] = (short)mm; bL[ct][j] = (short)ll;
            }
        }
#pragma unroll
        for (int ct = 0; ct < 6; ++ct) {
            acc[ct] = __builtin_amdgcn_mfma_f32_16x16x32_bf16(aH, bH[ct], acc[ct], 0, 0, 0);
            acc[ct] = __builtin_amdgcn_mfma_f32_16x16x32_bf16(aH, bM[ct], acc[ct], 0, 0, 0);
            acc[ct] = __builtin_amdgcn_mfma_f32_16x16x32_bf16(aM, bH[ct], acc[ct], 0, 0, 0);
            acc[ct] = __builtin_amdgcn_mfma_f32_16x16x32_bf16(aH, bL[ct], acc[ct], 0, 0, 0);
            acc[ct] = __builtin_amdgcn_mfma_f32_16x16x32_bf16(aM, bM[ct], acc[ct], 0, 0, 0);
            acc[ct] = __builtin_amdgcn_mfma_f32_16x16x32_bf16(aL, bH[ct], acc[ct], 0, 0, 0);
        }
    }

    float* Qtf = ws + QTF_OFF + (size_t)b * PT_EL;
#pragma unroll
    for (int ct = 0; ct < 6; ++ct)
#pragma unroll
        for (int r = 0; r < 4; ++r) {
            int row = h * 64 + wave * 16 + quad * 4 + r;
            int col = cg * 96 + ct * 16 + lm;
            Qtf[row * C_IN + col] = acc[ct][r];
        }
}

// ---------------- attn: sim = Qt*Wk^T (Qt split3 on read) -> softmax -> Z. grid (NB,NH)=16 ----------------
__global__ __launch_bounds__(256) void attn_kernel(float* __restrict__ ws) {
    int b = blockIdx.x, h = blockIdx.y;
    int tid  = threadIdx.x;
    int wave = tid >> 6;
    int lane = tid & 63;
    int lm   = lane & 15, quad = lane >> 4;

    __shared__ float At[64 * 68];   // attn^T [j][i]

    const float* Qtf = ws + QTF_OFF + (size_t)b * PT_EL;
    const unsigned short* KH = (const unsigned short*)(ws + WKH_OFF);
    const unsigned short* KM = (const unsigned short*)(ws + WKM_OFF);
    const unsigned short* KL = (const unsigned short*)(ws + WKL_OFF);
    const unsigned short* WOHp = (const unsigned short*)(ws + WOH_OFF);
    const unsigned short* WOLp = (const unsigned short*)(ws + WOL_OFF);

    // ---- C1: sim = Qt * Wk_h^T (64x64, K=192), Qt split3 on read ----
    f32x4 sacc[4];
#pragma unroll
    for (int ct = 0; ct < 4; ++ct) sacc[ct] = (f32x4){0.f, 0.f, 0.f, 0.f};

    int ar = (h * 64 + wave * 16 + lm) * C_IN;
#pragma unroll
    for (int ch = 0; ch < 6; ++ch) {
        int k0 = ch * 32 + quad * 8;
        float4 q0 = *(const float4*)(Qtf + ar + k0);
        float4 q1 = *(const float4*)(Qtf + ar + k0 + 4);
        short8 bH[4], bM[4], bL[4];
#pragma unroll
        for (int ct = 0; ct < 4; ++ct) {
            int kr = (h * 64 + ct * 16 + lm) * C_IN + k0;
            bH[ct] = *(const short8*)(KH + kr);
            bM[ct] = *(const short8*)(KM + kr);
            bL[ct] = *(const short8*)(KL + kr);
        }
        float qv[8];
        *(float4*)&qv[0] = q0;
        *(float4*)&qv[4] = q1;
        short8 aH, aM, aL;
#pragma unroll
        for (int j = 0; j < 8; ++j) {
            unsigned short hh, mm, ll;
            split3_bf(qv[j], hh, mm, ll);
            aH[j] = (short)hh; aM[j] = (short)mm; aL[j] = (short)ll;
        }
#pragma unroll
        for (int ct = 0; ct < 4; ++ct) {
            sacc[ct] = __builtin_amdgcn_mfma_f32_16x16x32_bf16(aH, bH[ct], sacc[ct], 0, 0, 0);
            sacc[ct] = __builtin_amdgcn_mfma_f32_16x16x32_bf16(aH, bM[ct], sacc[ct], 0, 0, 0);
            sacc[ct] = __builtin_amdgcn_mfma_f32_16x16x32_bf16(aM, bH[ct], sacc[ct], 0, 0, 0);
            sacc[ct] = __builtin_amdgcn_mfma_f32_16x16x32_bf16(aH, bL[ct], sacc[ct], 0, 0, 0);
            sacc[ct] = __builtin_amdgcn_mfma_f32_16x16x32_bf16(aM, bM[ct], sacc[ct], 0, 0, 0);
            sacc[ct] = __builtin_amdgcn_mfma_f32_16x16x32_bf16(aL, bH[ct], sacc[ct], 0, 0, 0);
        }
    }

    // ---- softmax over j (cols), store attn^T into At[j][i] ----
#pragma unroll
    for (int r = 0; r < 4; ++r) {
        float s0 = sacc[0][r] * ATT_SCALE;
        float s1 = sacc[1][r] * ATT_SCALE;
        float s2 = sacc[2][r] * ATT_SCALE;
        float s3 = sacc[3][r] * ATT_SCALE;
        float mx = fmaxf(fmaxf(s0, s1), fmaxf(s2, s3));
        mx = fmaxf(mx, __shfl_xor(mx, 1));
        mx = fmaxf(mx, __shfl_xor(mx, 2));
        mx = fmaxf(mx, __shfl_xor(mx, 4));
        mx = fmaxf(mx, __shfl_xor(mx, 8));
        float e0 = __expf(s0 - mx), e1 = __expf(s1 - mx);
        float e2 = __expf(s2 - mx), e3 = __expf(s3 - mx);
        float sum = (e0 + e1) + (e2 + e3);
        sum += __shfl_xor(sum, 1);
        sum += __shfl_xor(sum, 2);
        sum += __shfl_xor(sum, 4);
        sum += __shfl_xor(sum, 8);
        float inv = 1.0f / sum;
        int i = wave * 16 + quad * 4 + r;
        At[lm * 68 + i]        = e0 * inv;
        At[(16 + lm) * 68 + i] = e1 * inv;
        At[(32 + lm) * 68 + i] = e2 * inv;
        At[(48 + lm) * 68 + i] = e3 * inv;
    }
    __syncthreads();

    // ---- C2: Z_h = Wo[:, 64h:64h+64] * attn (192x64), double-split ----
    f32x4 zacc[3][4];
#pragma unroll
    for (int mt = 0; mt < 3; ++mt)
#pragma unroll
        for (int ct = 0; ct < 4; ++ct) zacc[mt][ct] = (f32x4){0.f, 0.f, 0.f, 0.f};

#pragma unroll
    for (int ch = 0; ch < 2; ++ch) {
        int k0 = ch * 32 + quad * 8;
        short8 bH[4], bL[4];
#pragma unroll
        for (int ct = 0; ct < 4; ++ct) {
            float av[8];
            *(float4*)&av[0] = *(const float4*)&At[(ct * 16 + lm) * 68 + k0];
            *(float4*)&av[4] = *(const float4*)&At[(ct * 16 + lm) * 68 + k0 + 4];
#pragma unroll
            for (int j = 0; j < 8; ++j) {
                unsigned short hh, ll;
                split_bf(av[j], hh, ll);
                bH[ct][j] = (short)hh; bL[ct][j] = (short)ll;
            }
        }
#pragma unroll
        for (int mt = 0; mt < 3; ++mt) {
            int orow = (wave * 48 + mt * 16 + lm) * 512 + h * 64 + k0;
            short8 aH = *(const short8*)(WOHp + orow);
            short8 aL = *(const short8*)(WOLp + orow);
#pragma unroll
            for (int ct = 0; ct < 4; ++ct) {
                zacc[mt][ct] = __builtin_amdgcn_mfma_f32_16x16x32_bf16(aH, bH[ct], zacc[mt][ct], 0, 0, 0);
                zacc[mt][ct] = __builtin_amdgcn_mfma_f32_16x16x32_bf16(aH, bL[ct], zacc[mt][ct], 0, 0, 0);
                zacc[mt][ct] = __builtin_amdgcn_mfma_f32_16x16x32_bf16(aL, bH[ct], zacc[mt][ct], 0, 0, 0);
            }
        }
    }

    unsigned short* ZHb = (unsigned short*)(ws + ZH_OFF) + (size_t)b * ZEL;
    unsigned short* ZLb = (unsigned short*)(ws + ZL_OFF) + (size_t)b * ZEL;
#pragma unroll
    for (int mt = 0; mt < 3; ++mt)
#pragma unroll
        for (int r = 0; r < 4; ++r) {
            int o = wave * 48 + mt * 16 + quad * 4 + r;
#pragma unroll
            for (int ct = 0; ct < 4; ++ct) {
                unsigned short hh, ll;
                split_bf(zacc[mt][ct][r], hh, ll);
                int idx = o * 512 + h * 64 + ct * 16 + lm;
                ZHb[idx] = hh;
                ZLb[idx] = ll;
            }
        }
}

// ---------------- wmix_f: W += Z*Wv^T per kseg, fp32 atomics. grid (NB,4,8)=64 blk ----------------
__global__ __launch_bounds__(256) void wmix_f(float* __restrict__ ws) {
    int b = blockIdx.x;
    int half = blockIdx.y >> 1, cwD = blockIdx.y & 1;
    int kseg = blockIdx.z;
    int tid  = threadIdx.x;
    int wave = tid >> 6, lane = tid & 63;
    int lm = lane & 15, quad = lane >> 4;
    int rw = wave;

    const unsigned short* ZHb = (const unsigned short*)(ws + ZH_OFF) + (size_t)b * ZEL;
    const unsigned short* ZLb = (const unsigned short*)(ws + ZL_OFF) + (size_t)b * ZEL;
    const unsigned short* VTH = (const unsigned short*)(ws + WVTH_OFF);
    const unsigned short* VTL = (const unsigned short*)(ws + WVTL_OFF);

    f32x4 acc[3][3];
#pragma unroll
    for (int mt = 0; mt < 3; ++mt)
#pragma unroll
        for (int ct = 0; ct < 3; ++ct) acc[mt][ct] = (f32x4){0.f, 0.f, 0.f, 0.f};

#pragma unroll
    for (int ch = 0; ch < 2; ++ch) {
        int k0 = kseg * 64 + ch * 32 + quad * 8;
        short8 aH[3], aL[3];
#pragma unroll
        for (int mt = 0; mt < 3; ++mt) {
            int o = (rw * 48 + mt * 16 + lm) * 512 + k0;
            aH[mt] = *(const short8*)(ZHb + o);
            aL[mt] = *(const short8*)(ZLb + o);
        }
        short8 bH[3], bL[3];
#pragma unroll
        for (int ct = 0; ct < 3; ++ct) {
            int c = (half * 96 + cwD * 48 + ct * 16 + lm) * 512 + k0;
            bH[ct] = *(const short8*)(VTH + c);
            bL[ct] = *(const short8*)(VTL + c);
        }
#pragma unroll
        for (int ct = 0; ct < 3; ++ct)
#pragma unroll
            for (int mt = 0; mt < 3; ++mt) {
                acc[mt][ct] = __builtin_amdgcn_mfma_f32_16x16x32_bf16(aH[mt], bH[ct], acc[mt][ct], 0, 0, 0);
                acc[mt][ct] = __builtin_amdgcn_mfma_f32_16x16x32_bf16(aH[mt], bL[ct], acc[mt][ct], 0, 0, 0);
                acc[mt][ct] = __builtin_amdgcn_mfma_f32_16x16x32_bf16(aL[mt], bH[ct], acc[mt][ct], 0, 0, 0);
            }
    }

    float* Wb = ws + WF_OFF + (size_t)b * GEL;
#pragma unroll
    for (int mt = 0; mt < 3; ++mt)
#pragma unroll
        for (int r = 0; r < 4; ++r) {
            int m = rw * 48 + mt * 16 + quad * 4 + r;
#pragma unroll
            for (int ct = 0; ct < 3; ++ct)
                atomicAdd(&Wb[m * C_IN + half * 96 + cwD * 48 + ct * 16 + lm], acc[mt][ct][r]);
        }
}

// ---------------- final: out = W*x + bo, W fp32 -> bf16 inline. grid (256,NB) ----------------
__global__ __launch_bounds__(256) void final_f(const float* __restrict__ x,
                                               const float* __restrict__ ws_wf,
                                               const float* __restrict__ bo,
                                               float* __restrict__ out) {
    int n0 = blockIdx.x * 128;
    int b  = blockIdx.y;

    __shared__ unsigned short Xs[128 * 40];

    int tid  = threadIdx.x;
    int wave = tid >> 6;
    int lane = tid & 63;
    int wm   = (wave & 1) * 96;
    int wn   = (wave >> 1) * 64;
    int lm   = lane & 15, quad = lane >> 4;

    int sn  = tid & 127;
    int skh = (tid >> 7) * 16;

    const float* xsrc = x + (size_t)b * C_IN * S_TOT + n0 + sn;
    const float* Wb = ws_wf + (size_t)b * GEL;

    f32x4 acc[6][4];
#pragma unroll
    for (int mt = 0; mt < 6; mt++)
#pragma unroll
        for (int nt = 0; nt < 4; nt++) acc[mt][nt] = (f32x4){0.f, 0.f, 0.f, 0.f};

    float pf[16];
#pragma unroll
    for (int j = 0; j < 16; j++) pf[j] = xsrc[(size_t)(skh + j) * S_TOT];

    for (int kc = 0; kc < 6; ++kc) {
        int k0 = kc * 32;
        __syncthreads();
        {
            union { uint4 q; unsigned int u[4]; } pk0, pk1;
#pragma unroll
            for (int j = 0; j < 4; j++) {
                pk0.u[j] = pk_bf16(pf[2 * j],     pf[2 * j + 1]);
                pk1.u[j] = pk_bf16(pf[8 + 2 * j], pf[8 + 2 * j + 1]);
            }
            *(uint4*)&Xs[sn * 40 + skh + 0] = pk0.q;
            *(uint4*)&Xs[sn * 40 + skh + 8] = pk1.q;
        }
        __syncthreads();
        if (kc + 1 < 6) {
            int kn = k0 + 32;
#pragma unroll
            for (int j = 0; j < 16; j++) pf[j] = xsrc[(size_t)(kn + skh + j) * S_TOT];
        }

        short8 afr[6];
#pragma unroll
        for (int mt = 0; mt < 6; mt++) {
            const float* wr = Wb + (size_t)(wm + mt * 16 + lm) * C_IN + k0 + quad * 8;
            float4 w0 = *(const float4*)(wr);
            float4 w1 = *(const float4*)(wr + 4);
            short8 a;
            a[0] = (short)f2bf(w0.x); a[1] = (short)f2bf(w0.y);
            a[2] = (short)f2bf(w0.z); a[3] = (short)f2bf(w0.w);
            a[4] = (short)f2bf(w1.x); a[5] = (short)f2bf(w1.y);
            a[6] = (short)f2bf(w1.z); a[7] = (short)f2bf(w1.w);
            afr[mt] = a;
        }
#pragma unroll
        for (int nt = 0; nt < 4; nt++) {
            short8 bfr = *(const short8*)&Xs[(wn + nt * 16 + lm) * 40 + quad * 8];
#pragma unroll
            for (int mt = 0; mt < 6; mt++)
                acc[mt][nt] = __builtin_amdgcn_mfma_f32_16x16x32_bf16(afr[mt], bfr, acc[mt][nt], 0, 0, 0);
        }
    }

#pragma unroll
    for (int mt = 0; mt < 6; mt++) {
#pragma unroll
        for (int r = 0; r < 4; r++) {
            int m = wm + mt * 16 + quad * 4 + r;
            float bias = bo[m];
            float* op = out + ((size_t)b * C_IN + m) * S_TOT + n0;
#pragma unroll
            for (int nt = 0; nt < 4; nt++)
                op[wn + nt * 16 + lm] = acc[mt][nt][r] + bias;
        }
    }
}

// ---------------- Gram fallback (fp32 atomic; used only if ws too small) ----------------
__global__ __launch_bounds__(512, 2) void gram_atomic(const float* __restrict__ x,
                                                      float* __restrict__ G) {
    int b     = blockIdx.y;
    int kbase = blockIdx.x * (GR_CH * GR_BK);

    __shared__ float Ls[GR_BK][196];

    int tid = threadIdx.x;
    int tx  = tid & 15;
    int tyy = tid >> 4;

    const float* xb = x + (size_t)b * C_IN * S_TOT;

    int lc[3], lkq[3];
#pragma unroll
    for (int q = 0; q < 3; q++) { int id = tid + 512 * q; lc[q] = id >> 3; lkq[q] = id & 7; }

    float acc[6][12] = {};
    float4 pf[3];

#pragma unroll
    for (int q = 0; q < 3; q++)
        pf[q] = *(const float4*)(xb + (size_t)lc[q] * S_TOT + kbase + lkq[q] * 4);

    for (int ch = 0; ch < GR_CH; ++ch) {
        __syncthreads();
#pragma unroll
        for (int q = 0; q < 3; q++) {
            Ls[lkq[q] * 4 + 0][lc[q]] = pf[q].x;
            Ls[lkq[q] * 4 + 1][lc[q]] = pf[q].y;
            Ls[lkq[q] * 4 + 2][lc[q]] = pf[q].z;
            Ls[lkq[q] * 4 + 3][lc[q]] = pf[q].w;
        }
        __syncthreads();
        if (ch + 1 < GR_CH) {
            int k0 = kbase + (ch + 1) * GR_BK;
#pragma unroll
            for (int q = 0; q < 3; q++)
                pf[q] = *(const float4*)(xb + (size_t)lc[q] * S_TOT + k0 + lkq[q] * 4);
        }
#pragma unroll
        for (int kk = 0; kk < GR_BK; ++kk) {
            float a[6], bb[12];
#pragma unroll
            for (int rr = 0; rr < 6; ++rr)  a[rr] = Ls[kk][tyy + 32 * rr];
#pragma unroll
            for (int cc = 0; cc < 12; ++cc) bb[cc] = Ls[kk][tx + 16 * cc];
#pragma unroll
            for (int rr = 0; rr < 6; ++rr)
#pragma unroll
                for (int cc = 0; cc < 12; ++cc)
                    acc[rr][cc] = fmaf(a[rr], bb[cc], acc[rr][cc]);
        }
    }

    float* Gb = G + b * C_IN * C_IN;
#pragma unroll
    for (int rr = 0; rr < 6; ++rr)
#pragma unroll
        for (int cc = 0; cc < 12; ++cc)
            atomicAdd(&Gb[(tyy + 32 * rr) * C_IN + tx + 16 * cc], acc[rr][cc]);
}

// ---------------- generic 64x64-tile GEMM (fp32 out; fallback path) ----------------
__global__ __launch_bounds__(256) void gemm64_kernel(const float* __restrict__ A,
                                                     const float* __restrict__ B,
                                                     float* __restrict__ C,
                                                     int K, int N,
                                                     long aStride, long bStride, long cStride) {
    int mi0 = blockIdx.x * 64;
    int nj0 = blockIdx.y * 64;
    int b   = blockIdx.z;

    __shared__ float As[16][68];
    __shared__ float Bs[16][68];

    int tid = threadIdx.x;
    int tx = tid & 15, ty = tid >> 4;
    int lrow = tid >> 2, lk = (tid & 3) * 4;
    int ldk = tid >> 4, ldn = (tid & 15) * 4;

    const float* Ab = A + b * aStride;
    const float* Bb = B + b * bStride;

    float acc[4][4] = {};

    for (int k0 = 0; k0 < K; k0 += 16) {
        float4 av = *(const float4*)(Ab + (size_t)(mi0 + lrow) * K + k0 + lk);
        float4 bv = *(const float4*)(Bb + (size_t)(k0 + ldk) * N + nj0 + ldn);
        __syncthreads();
        As[lk + 0][lrow] = av.x; As[lk + 1][lrow] = av.y;
        As[lk + 2][lrow] = av.z; As[lk + 3][lrow] = av.w;
        *(float4*)&Bs[ldk][ldn] = bv;
        __syncthreads();
#pragma unroll
        for (int kk = 0; kk < 16; kk++) {
            float4 a = *(const float4*)&As[kk][ty * 4];
            float4 bb = *(const float4*)&Bs[kk][tx * 4];
            acc[0][0] += a.x * bb.x; acc[0][1] += a.x * bb.y; acc[0][2] += a.x * bb.z; acc[0][3] += a.x * bb.w;
            acc[1][0] += a.y * bb.x; acc[1][1] += a.y * bb.y; acc[1][2] += a.y * bb.z; acc[1][3] += a.y * bb.w;
            acc[2][0] += a.z * bb.x; acc[2][1] += a.z * bb.y; acc[2][2] += a.z * bb.z; acc[2][3] += a.z * bb.w;
            acc[3][0] += a.w * bb.x; acc[3][1] += a.w * bb.y; acc[3][2] += a.w * bb.z; acc[3][3] += a.w * bb.w;
        }
    }

    float* Cb = C + b * cStride;
#pragma unroll
    for (int r = 0; r < 4; r++) {
        float4 v = { acc[r][0], acc[r][1], acc[r][2], acc[r][3] };
        *(float4*)(Cb + (size_t)(mi0 + ty * 4 + r) * N + nj0 + tx * 4) = v;
    }
}

// ---------------- same GEMM, bf16 packed output (fallback path) ----------------
__global__ __launch_bounds__(256) void gemm64bf_kernel(const float* __restrict__ A,
                                                       const float* __restrict__ B,
                                                       unsigned short* __restrict__ C,
                                                       int K, int N,
                                                       long aStride, long bStride, long cStride) {
    int mi0 = blockIdx.x * 64;
    int nj0 = blockIdx.y * 64;
    int b   = blockIdx.z;

    __shared__ float As[16][68];
    __shared__ float Bs[16][68];

    int tid = threadIdx.x;
    int tx = tid & 15, ty = tid >> 4;
    int lrow = tid >> 2, lk = (tid & 3) * 4;
    int ldk = tid >> 4, ldn = (tid & 15) * 4;

    const float* Ab = A + b * aStride;
    const float* Bb = B + b * bStride;

    float acc[4][4] = {};

    for (int k0 = 0; k0 < K; k0 += 16) {
        float4 av = *(const float4*)(Ab + (size_t)(mi0 + lrow) * K + k0 + lk);
        float4 bv = *(const float4*)(Bb + (size_t)(k0 + ldk) * N + nj0 + ldn);
        __syncthreads();
        As[lk + 0][lrow] = av.x; As[lk + 1][lrow] = av.y;
        As[lk + 2][lrow] = av.z; As[lk + 3][lrow] = av.w;
        *(float4*)&Bs[ldk][ldn] = bv;
        __syncthreads();
#pragma unroll
        for (int kk = 0; kk < 16; kk++) {
            float4 a = *(const float4*)&As[kk][ty * 4];
            float4 bb = *(const float4*)&Bs[kk][tx * 4];
            acc[0][0] += a.x * bb.x; acc[0][1] += a.x * bb.y; acc[0][2] += a.x * bb.z; acc[0][3] += a.x * bb.w;
            acc[1][0] += a.y * bb.x; acc[1][1] += a.y * bb.y; acc[1][2] += a.y * bb.z; acc[1][3] += a.y * bb.w;
            acc[2][0] += a.z * bb.x; acc[2][1] += a.z * bb.y; acc[2][2] += a.z * bb.z; acc[2][3] += a.z * bb.w;
            acc[3][0] += a.w * bb.x; acc[3][1] += a.w * bb.y; acc[3][2] += a.w * bb.z; acc[3][3] += a.w * bb.w;
        }
    }

    unsigned short* Cb = C + b * cStride;
#pragma unroll
    for (int r = 0; r < 4; r++) {
        union { unsigned long long q; unsigned int u[2]; } pk;
        pk.u[0] = pk_bf16(acc[r][0], acc[r][1]);
        pk.u[1] = pk_bf16(acc[r][2], acc[r][3]);
        *(unsigned long long*)&Cb[(size_t)(mi0 + ty * 4 + r) * N + nj0 + tx * 4] = pk.q;
    }
}

// ---------------- fallback fused sim/softmax/M ----------------
__global__ __launch_bounds__(256) void simsoftm_kernel(const float* __restrict__ T,
                                                       const float* __restrict__ wk,
                                                       const float* __restrict__ wv,
                                                       float* __restrict__ M) {
    int b = blockIdx.x, h = blockIdx.y;

    __shared__ float As[16][68];
    __shared__ float Bs[16][68];
    __shared__ float At[64][68];

    int tid = threadIdx.x;
    int tx = tid & 15, ty = tid >> 4;
    int ldk = tid >> 4, ldn = (tid & 15) * 4;
    int lrow = tid >> 2, lk = (tid & 3) * 4;

    const float* Th  = T + (size_t)b * 512 * C_IN + (size_t)(h * 64) * C_IN;
    const float* wkh = wk + (size_t)(h * 64) * C_IN;
    const float* wvh = wv + (size_t)(h * 64) * C_IN;

    float acc[4][4] = {};
    for (int k0 = 0; k0 < C_IN; k0 += 16) {
        float4 av = *(const float4*)(Th  + (size_t)lrow * C_IN + k0 + lk);
        float4 bv = *(const float4*)(wkh + (size_t)lrow * C_IN + k0 + lk);
        __syncthreads();
        As[lk + 0][lrow] = av.x; As[lk + 1][lrow] = av.y;
        As[lk + 2][lrow] = av.z; As[lk + 3][lrow] = av.w;
        Bs[lk + 0][lrow] = bv.x; Bs[lk + 1][lrow] = bv.y;
        Bs[lk + 2][lrow] = bv.z; Bs[lk + 3][lrow] = bv.w;
        __syncthreads();
#pragma unroll
        for (int kk = 0; kk < 16; kk++) {
            float4 a = *(const float4*)&As[kk][ty * 4];
            float4 bb = *(const float4*)&Bs[kk][tx * 4];
            acc[0][0] += a.x * bb.x; acc[0][1] += a.x * bb.y; acc[0][2] += a.x * bb.z; acc[0][3] += a.x * bb.w;
            acc[1][0] += a.y * bb.x; acc[1][1] += a.y * bb.y; acc[1][2] += a.y * bb.z; acc[1][3] += a.y * bb.w;
            acc[2][0] += a.z * bb.x; acc[2][1] += a.z * bb.y; acc[2][2] += a.z * bb.z; acc[2][3] += a.z * bb.w;
            acc[3][0] += a.w * bb.x; acc[3][1] += a.w * bb.y; acc[3][2] += a.w * bb.z; acc[3][3] += a.w * bb.w;
        }
    }

#pragma unroll
    for (int r = 0; r < 4; r++) {
        float s0 = acc[r][0] * ATT_SCALE, s1 = acc[r][1] * ATT_SCALE;
        float s2 = acc[r][2] * ATT_SCALE, s3 = acc[r][3] * ATT_SCALE;
        float mx = fmaxf(fmaxf(s0, s1), fmaxf(s2, s3));
        mx = fmaxf(mx, __shfl_xor(mx, 1));
        mx = fmaxf(mx, __shfl_xor(mx, 2));
        mx = fmaxf(mx, __shfl_xor(mx, 4));
        mx = fmaxf(mx, __shfl_xor(mx, 8));
        float e0 = __expf(s0 - mx), e1 = __expf(s1 - mx);
        float e2 = __expf(s2 - mx), e3 = __expf(s3 - mx);
        float sum = (e0 + e1) + (e2 + e3);
        sum += __shfl_xor(sum, 1);
        sum += __shfl_xor(sum, 2);
        sum += __shfl_xor(sum, 4);
        sum += __shfl_xor(sum, 8);
        float inv = 1.0f / sum;
        At[tx * 4 + 0][ty * 4 + r] = e0 * inv;
        At[tx * 4 + 1][ty * 4 + r] = e1 * inv;
        At[tx * 4 + 2][ty * 4 + r] = e2 * inv;
        At[tx * 4 + 3][ty * 4 + r] = e3 * inv;
    }

    float* Mb = M + (size_t)b * 512 * C_IN + (size_t)(h * 64) * C_IN;
    for (int nj = 0; nj < C_IN; nj += 64) {
        float acc2[4][4] = {};
        for (int j0 = 0; j0 < 64; j0 += 16) {
            float4 bv = *(const float4*)(wvh + (size_t)(j0 + ldk) * C_IN + nj + ldn);
            __syncthreads();
            *(float4*)&Bs[ldk][ldn] = bv;
            __syncthreads();
#pragma unroll
            for (int kk = 0; kk < 16; kk++) {
                float4 a = *(const float4*)&At[j0 + kk][ty * 4];
                float4 bb = *(const float4*)&Bs[kk][tx * 4];
                acc2[0][0] += a.x * bb.x; acc2[0][1] += a.x * bb.y; acc2[0][2] += a.x * bb.z; acc2[0][3] += a.x * bb.w;
                acc2[1][0] += a.y * bb.x; acc2[1][1] += a.y * bb.y; acc2[1][2] += a.y * bb.z; acc2[1][3] += a.y * bb.w;
                acc2[2][0] += a.z * bb.x; acc2[2][1] += a.z * bb.y; acc2[2][2] += a.z * bb.z; acc2[2][3] += a.z * bb.w;
                acc2[3][0] += a.w * bb.x; acc2[3][1] += a.w * bb.y; acc2[3][2] += a.w * bb.z; acc2[3][3] += a.w * bb.w;
            }
        }
#pragma unroll
        for (int r = 0; r < 4; r++) {
            float4 v = { acc2[r][0], acc2[r][1], acc2[r][2], acc2[r][3] };
            *(float4*)(Mb + (size_t)(ty * 4 + r) * C_IN + nj + tx * 4) = v;
        }
    }
}

// ---------------- fallback final (bf16 W) ----------------
__global__ __launch_bounds__(256) void final_kernel(const float* __restrict__ x,
                                                    const unsigned short* __restrict__ Wbf,
                                                    const float* __restrict__ bo,
                                                    float* __restrict__ out) {
    int n0 = blockIdx.x * 128;
    int b  = blockIdx.y;

    __shared__ unsigned short Xs[128 * 40];

    int tid  = threadIdx.x;
    int wave = tid >> 6;
    int lane = tid & 63;
    int wm   = (wave & 1) * 96;
    int wn   = (wave >> 1) * 64;
    int lm   = lane & 15, quad = lane >> 4;

    int sn  = tid & 127;
    int skh = (tid >> 7) * 16;

    const float* xsrc = x + (size_t)b * C_IN * S_TOT + n0 + sn;
    const unsigned short* Wb = Wbf + b * C_IN * C_IN;

    f32x4 acc[6][4];
#pragma unroll
    for (int mt = 0; mt < 6; mt++)
#pragma unroll
        for (int nt = 0; nt < 4; nt++) acc[mt][nt] = (f32x4){0.f, 0.f, 0.f, 0.f};

    float pf[16];
#pragma unroll
    for (int j = 0; j < 16; j++) pf[j] = xsrc[(size_t)(skh + j) * S_TOT];

    for (int kc = 0; kc < 6; ++kc) {
        int k0 = kc * 32;
        __syncthreads();
        {
            union { uint4 q; unsigned int u[4]; } pk0, pk1;
#pragma unroll
            for (int j = 0; j < 4; j++) {
                pk0.u[j] = pk_bf16(pf[2 * j],     pf[2 * j + 1]);
                pk1.u[j] = pk_bf16(pf[8 + 2 * j], pf[8 + 2 * j + 1]);
            }
            *(uint4*)&Xs[sn * 40 + skh + 0] = pk0.q;
            *(uint4*)&Xs[sn * 40 + skh + 8] = pk1.q;
        }
        __syncthreads();
        if (kc + 1 < 6) {
            int kn = k0 + 32;
#pragma unroll
            for (int j = 0; j < 16; j++) pf[j] = xsrc[(size_t)(kn + skh + j) * S_TOT];
        }

        short8 afr[6];
#pragma unroll
        for (int mt = 0; mt < 6; mt++)
            afr[mt] = *(const short8*)(Wb + (size_t)(wm + mt * 16 + lm) * C_IN + k0 + quad * 8);
#pragma unroll
        for (int nt = 0; nt < 4; nt++) {
            short8 bfr = *(const short8*)&Xs[(wn + nt * 16 + lm) * 40 + quad * 8];
#pragma unroll
            for (int mt = 0; mt < 6; mt++)
                acc[mt][nt] = __builtin_amdgcn_mfma_f32_16x16x32_bf16(afr[mt], bfr, acc[mt][nt], 0, 0, 0);
        }
    }

#pragma unroll
    for (int mt = 0; mt < 6; mt++) {
#pragma unroll
        for (int r = 0; r < 4; r++) {
            int m = wm + mt * 16 + quad * 4 + r;
            float bias = bo[m];
            float* op = out + ((size_t)b * C_IN + m) * S_TOT + n0;
#pragma unroll
            for (int nt = 0; nt < 4; nt++)
                op[wn + nt * 16 + lm] = acc[mt][nt][r] + bias;
        }
    }
}

extern "C" void kernel_launch(void* const* d_in, const int* in_sizes, int n_in,
                              void* d_out, int out_size, void* d_ws, size_t ws_size,
                              hipStream_t stream) {
    const float* x  = (const float*)d_in[0];
    const float* wq = (const float*)d_in[1];
    const float* wk = (const float*)d_in[2];
    const float* wv = (const float*)d_in[3];
    const float* wo = (const float*)d_in[4];
    const float* bo = (const float*)d_in[5];
    float* out = (float*)d_out;
    float* ws  = (float*)d_ws;

    bool bigws = ws_size >= (size_t)WS_END * sizeof(float);
    if (bigws) {
        // 6 dispatches, no barriers, every grid sized for its bandwidth:
        gram_partial<<<dim3(NSLICE, NB), 512, 0, stream>>>(x, wq, wk, wv, wo, ws);
        greduce<<<dim3(36, 8, NB), 256, 0, stream>>>(ws);
        proj_kernel<<<dim3(NB, NH, 2), 256, 0, stream>>>(ws);
        attn_kernel<<<dim3(NB, NH), 256, 0, stream>>>(ws);
        wmix_f<<<dim3(NB, 4, 8), 256, 0, stream>>>(ws);
        final_f<<<dim3(256, NB), 256, 0, stream>>>(x, ws + WF_OFF, bo, out);
    } else {
        // fallback: original proven chain
        float* gG = ws + G_OFF;
        float* gT = ws + T_OFF;
        float* gM = ws + M_OFF;
        unsigned short* gWbf = (unsigned short*)(ws + WBF_OFF);
        hipMemsetAsync(gG, 0, G_SZ * sizeof(float), stream);
        gram_atomic<<<dim3(NSLICE, NB), 512, 0, stream>>>(x, gG);
        gemm64_kernel<<<dim3(8, 3, NB), 256, 0, stream>>>(
            wq, gG, gT, C_IN, C_IN, 0L, (long)(C_IN * C_IN), (long)(512 * C_IN));
        simsoftm_kernel<<<dim3(NB, NH), 256, 0, stream>>>(gT, wk, wv, gM);
        gemm64bf_kernel<<<dim3(3, 3, NB), 256, 0, stream>>>(
            wo, gM, gWbf, 512, C_IN, 0L, (long)(512 * C_IN), (long)(C_IN * C_IN));
        final_kernel<<<dim3(256, NB), 256, 0, stream>>>(x, gWbf, bo, out);
    }
}